// Round 2
// baseline (13990.410 us; speedup 1.0000x reference)
//
#include <hip/hip_runtime.h>
#include <hip/hip_bf16.h>
#include <math.h>

namespace {
constexpr int Bn = 8, Sn = 1024, Hn = 8, DHn = 256, HDn = 2048;
}

// ---------------------------------------------------------------------------
// Generic tiled fp32 GEMM: C = A @ W.
//   A rows are "tokens": m -> b = m/L, s = m%L, row index = b*a_batch + a_off + s
//   C rows:                              row index = b*c_batch + c_off + s
//   W is [K][N] row-major. N, K multiples of 64/16. M bounds-checked.
// ---------------------------------------------------------------------------
__global__ __launch_bounds__(256) void gemm_f32(
    const float* __restrict__ A, const float* __restrict__ W, float* __restrict__ C,
    int L, int K, int N, int a_batch, int a_off, int c_batch, int c_off, int M_total)
{
  __shared__ float As[16][64];
  __shared__ float Bs[16][64];
  const int tid = threadIdx.x;
  const int bn0 = blockIdx.x * 64;
  const int bm0 = blockIdx.y * 64;

  // A tile loader mapping: each thread loads a float4 along K
  const int a_ml = tid >> 2;            // 0..63  (m within tile)
  const int a_kq = (tid & 3) << 2;      // 0,4,8,12 (k within tile)
  const int mA = bm0 + a_ml;
  const bool a_valid = mA < M_total;
  int ab = 0, as = 0;
  if (a_valid) { ab = mA / L; as = mA - ab * L; }
  const float* a_ptr = A + (size_t)(ab * a_batch + a_off + as) * K + a_kq;

  // W tile loader mapping
  const int b_kl = tid >> 4;            // 0..15
  const int b_nq = (tid & 15) << 2;     // 0..60
  const float* b_ptr = W + (size_t)b_kl * N + bn0 + b_nq;

  const int ty = tid >> 4;              // 0..15 -> 4 rows
  const int tx = tid & 15;              // 0..15 -> 4 cols

  float acc[4][4] = {{0.f}};

  for (int k0 = 0; k0 < K; k0 += 16) {
    float4 av = make_float4(0.f, 0.f, 0.f, 0.f);
    if (a_valid) av = *(const float4*)(a_ptr + k0);
    const float4 bv = *(const float4*)(b_ptr + (size_t)k0 * N);
    As[a_kq + 0][a_ml] = av.x;
    As[a_kq + 1][a_ml] = av.y;
    As[a_kq + 2][a_ml] = av.z;
    As[a_kq + 3][a_ml] = av.w;
    *(float4*)&Bs[b_kl][b_nq] = bv;
    __syncthreads();
#pragma unroll
    for (int kk = 0; kk < 16; ++kk) {
      const float4 a4 = *(const float4*)&As[kk][ty << 2];
      const float4 b4 = *(const float4*)&Bs[kk][tx << 2];
      acc[0][0] += a4.x * b4.x; acc[0][1] += a4.x * b4.y; acc[0][2] += a4.x * b4.z; acc[0][3] += a4.x * b4.w;
      acc[1][0] += a4.y * b4.x; acc[1][1] += a4.y * b4.y; acc[1][2] += a4.y * b4.z; acc[1][3] += a4.y * b4.w;
      acc[2][0] += a4.z * b4.x; acc[2][1] += a4.z * b4.y; acc[2][2] += a4.z * b4.z; acc[2][3] += a4.z * b4.w;
      acc[3][0] += a4.w * b4.x; acc[3][1] += a4.w * b4.y; acc[3][2] += a4.w * b4.z; acc[3][3] += a4.w * b4.w;
    }
    __syncthreads();
  }

#pragma unroll
  for (int i = 0; i < 4; ++i) {
    const int m = bm0 + (ty << 2) + i;
    if (m < M_total) {
      const int cb = m / L, cs = m - cb * L;
      float* cp = C + (size_t)(cb * c_batch + c_off + cs) * N + bn0 + (tx << 2);
      cp[0] = acc[i][0]; cp[1] = acc[i][1]; cp[2] = acc[i][2]; cp[3] = acc[i][3];
    }
  }
}

// ---------------------------------------------------------------------------
// RoPE in place on Q [b][S][H*256] and K [b][S][256].
// Gemma-style: cos/sin duplicated across halves; pair (d, d+128), d<128.
// ---------------------------------------------------------------------------
__global__ __launch_bounds__(256) void rope_kernel(
    float* __restrict__ Q, float* __restrict__ Kb,
    const int* __restrict__ pos0, const int* __restrict__ pos1, const int* __restrict__ pos2)
{
  const int t = blockIdx.x;          // 0..B*S-1
  const int b = t >> 10, s = t & 1023;
  int p;
  if (s < 968)       p = pos0[b * 968 + s];
  else if (s < 974)  p = pos1[b * 6 + (s - 968)];
  else               p = pos2[b * 50 + (s - 974)];
  const float pf = (float)p;
  const float c0 = -0.07195578415606394f;  // -ln(10000)/128

  for (int idx = threadIdx.x; idx < 1152; idx += 256) {
    float* base;
    int d;
    if (idx < 1024) {  // Q pairs: h = idx/128, d = idx%128
      const int h = idx >> 7; d = idx & 127;
      base = Q + ((size_t)(b * Sn + s)) * HDn + h * DHn;
    } else {           // K pairs
      d = idx - 1024;
      base = Kb + ((size_t)(b * Sn + s)) * DHn;
    }
    const float inv = expf(c0 * (float)d);
    const float fr = pf * inv;
    float cs, sn;
    sincosf(fr, &sn, &cs);   // FIXED: sincosf(x, sin*, cos*)
    const float x1 = base[d], x2 = base[d + 128];
    base[d]       = x1 * cs - x2 * sn;
    base[d + 128] = x2 * cs + x1 * sn;
  }
}

// ---------------------------------------------------------------------------
// Attention, one block per (b, h, 16 q-rows). MQA: single KV head.
// scores = tanh((q.k/16)/50)*50 + mask; exact softmax; O written in place
// over Q (disjoint [rows x head-slice] per block; Q captured to LDS first).
// ---------------------------------------------------------------------------
__global__ __launch_bounds__(256) void attn_kernel(
    const float* __restrict__ Q, const float* __restrict__ Kb,
    const float* __restrict__ V, const float* __restrict__ mask,
    float* __restrict__ O)
{
  __shared__ float Qs[16][256];
  __shared__ float Sc[16][1024];
  const int q0 = blockIdx.x * 16;
  const int h  = blockIdx.y;
  const int b  = blockIdx.z;
  const int tid = threadIdx.x;

  // Phase 1: Q tile -> LDS (16 rows x 256), coalesced float4
  for (int e4 = tid; e4 < 1024; e4 += 256) {
    const int r = e4 >> 6, c4 = (e4 & 63) << 2;
    const float4 v = *(const float4*)(Q + ((size_t)(b * Sn + q0 + r)) * HDn + h * DHn + c4);
    *(float4*)&Qs[r][c4] = v;
  }
  __syncthreads();

  const int r  = tid >> 4;   // 0..15 (q row)
  const int kl = tid & 15;   // 0..15

  // Phase 2: scores (each thread: 64 scores for its row, cols kl::16)
  for (int kb = 0; kb < 64; ++kb) {
    const int ki = kb * 16 + kl;
    const float4* kp = (const float4*)(Kb + ((size_t)(b * Sn + ki)) * DHn);
    const float4* qp = (const float4*)&Qs[r][0];
    float ax = 0.f, ay = 0.f, az = 0.f, aw = 0.f;
#pragma unroll 8
    for (int d4 = 0; d4 < 64; ++d4) {
      const float4 kq = kp[d4];
      const float4 qq = qp[d4];
      ax += qq.x * kq.x; ay += qq.y * kq.y; az += qq.z * kq.z; aw += qq.w * kq.w;
    }
    const float sdot = (ax + ay) + (az + aw);
    float sc = 50.f * tanhf(sdot * (0.0625f / 50.f));
    sc += mask[((size_t)(b * Sn) + q0 + r) * (size_t)Sn + ki];
    Sc[r][ki] = sc;
  }
  __syncthreads();

  // Phase 3: softmax over each row (16 lanes per row; same wave)
  float lmax = -1e30f;
  for (int i = kl; i < 1024; i += 16) lmax = fmaxf(lmax, Sc[r][i]);
#pragma unroll
  for (int m = 1; m < 16; m <<= 1) lmax = fmaxf(lmax, __shfl_xor(lmax, m));
  float lsum = 0.f;
  for (int i = kl; i < 1024; i += 16) {
    const float e = expf(Sc[r][i] - lmax);
    Sc[r][i] = e;
    lsum += e;
  }
#pragma unroll
  for (int m = 1; m < 16; m <<= 1) lsum += __shfl_xor(lsum, m);
  const float rinv = 1.f / lsum;
  __syncthreads();

  // Phase 4: PV. thread (r, dg=kl) accumulates dims [kl*16, kl*16+16)
  float po[16] = {0.f};
  for (int ki = 0; ki < 1024; ++ki) {
    const float p = Sc[r][ki];
    const float4* vp = (const float4*)(V + ((size_t)(b * Sn + ki)) * DHn + kl * 16);
    const float4 v0 = vp[0], v1 = vp[1], v2 = vp[2], v3 = vp[3];
    po[0]  += p * v0.x; po[1]  += p * v0.y; po[2]  += p * v0.z; po[3]  += p * v0.w;
    po[4]  += p * v1.x; po[5]  += p * v1.y; po[6]  += p * v1.z; po[7]  += p * v1.w;
    po[8]  += p * v2.x; po[9]  += p * v2.y; po[10] += p * v2.z; po[11] += p * v2.w;
    po[12] += p * v3.x; po[13] += p * v3.y; po[14] += p * v3.z; po[15] += p * v3.w;
  }
  float* op = O + ((size_t)(b * Sn + q0 + r)) * HDn + h * DHn + kl * 16;
#pragma unroll
  for (int j = 0; j < 16; j += 4) {
    *(float4*)(op + j) = make_float4(po[j] * rinv, po[j + 1] * rinv, po[j + 2] * rinv, po[j + 3] * rinv);
  }
}

// ---------------------------------------------------------------------------
extern "C" void kernel_launch(void* const* d_in, const int* in_sizes, int n_in,
                              void* d_out, int out_size, void* d_ws, size_t ws_size,
                              hipStream_t stream) {
  (void)in_sizes; (void)n_in; (void)out_size; (void)ws_size;
  const float* hs0  = (const float*)d_in[0];
  const float* hs1  = (const float*)d_in[1];
  const float* hs2  = (const float*)d_in[2];
  const float* mask = (const float*)d_in[3];
  const int*   pos0 = (const int*)d_in[4];
  const int*   pos1 = (const int*)d_in[5];
  const int*   pos2 = (const int*)d_in[6];
  const float* wq[3] = {(const float*)d_in[7],  (const float*)d_in[11], (const float*)d_in[15]};
  const float* wk[3] = {(const float*)d_in[8],  (const float*)d_in[12], (const float*)d_in[16]};
  const float* wv[3] = {(const float*)d_in[9],  (const float*)d_in[13], (const float*)d_in[17]};
  const float* wo[3] = {(const float*)d_in[10], (const float*)d_in[14], (const float*)d_in[18]};
  float* out = (float*)d_out;

  // workspace: Q [8][1024][2048] | K [8][1024][256] | V [8][1024][256]  (80 MB)
  float* Qb = (float*)d_ws;
  float* Kb = Qb + (size_t)Bn * Sn * HDn;
  float* Vb = Kb + (size_t)Bn * Sn * DHn;

  const int  Ls[3]   = {968, 6, 50};
  const int  offs[3] = {0, 968, 974};
  const int  hid[3]  = {2048, 1024, 1024};
  const float* hs[3] = {hs0, hs1, hs2};

  dim3 blk(256);
  // QKV projections into Q/K/V buffers (concatenated sequence layout)
  for (int g = 0; g < 3; ++g) {
    const int L = Ls[g], Kd = hid[g], off = offs[g], M = Bn * L;
    dim3 gq(HDn / 64, (M + 63) / 64);
    hipLaunchKernelGGL(gemm_f32, gq, blk, 0, stream, hs[g], wq[g], Qb, L, Kd, HDn, L, 0, Sn, off, M);
    dim3 gk(DHn / 64, (M + 63) / 64);
    hipLaunchKernelGGL(gemm_f32, gk, blk, 0, stream, hs[g], wk[g], Kb, L, Kd, DHn, L, 0, Sn, off, M);
    hipLaunchKernelGGL(gemm_f32, gk, blk, 0, stream, hs[g], wv[g], Vb, L, Kd, DHn, L, 0, Sn, off, M);
  }

  // RoPE in place on Q and K
  hipLaunchKernelGGL(rope_kernel, dim3(Bn * Sn), blk, 0, stream, Qb, Kb, pos0, pos1, pos2);

  // Attention (output in place over Q)
  hipLaunchKernelGGL(attn_kernel, dim3(Sn / 16, Hn, Bn), blk, 0, stream, Qb, Kb, Vb, mask, Qb);

  // Output projections -> d_out (concatenated in return order)
  size_t ooff = 0;
  for (int g = 0; g < 3; ++g) {
    const int L = Ls[g], N = hid[g], off = offs[g], M = Bn * L;
    dim3 go(N / 64, (M + 63) / 64);
    hipLaunchKernelGGL(gemm_f32, go, blk, 0, stream, Qb, wo[g], out + ooff, L, HDn, N, Sn, off, L, 0, M);
    ooff += (size_t)M * N;
  }
}

// Round 3
// 3574.033 us; speedup vs baseline: 3.9145x; 3.9145x over previous
//
#include <hip/hip_runtime.h>
#include <hip/hip_bf16.h>
#include <math.h>

namespace {
constexpr int Bn = 8, Sn = 1024, Hn = 8, DHn = 256, HDn = 2048;
}

using bf16x8 = __attribute__((ext_vector_type(8))) short;
using f32x4  = __attribute__((ext_vector_type(4))) float;

__device__ __forceinline__ float bf2f(unsigned short u) {
  unsigned int x = ((unsigned int)u) << 16;
  return __builtin_bit_cast(float, x);
}
__device__ __forceinline__ unsigned short f2bf(float f) {
  unsigned int x = __builtin_bit_cast(unsigned int, f);
  x += 0x7fff + ((x >> 16) & 1);   // RNE (no NaN inputs expected)
  return (unsigned short)(x >> 16);
}

__device__ __forceinline__ float4 ld4(const float* p) { return *(const float4*)p; }
__device__ __forceinline__ float4 ld4(const unsigned short* p) {
  ushort4 u = *(const ushort4*)p;
  return make_float4(bf2f(u.x), bf2f(u.y), bf2f(u.z), bf2f(u.w));
}
__device__ __forceinline__ void st4(float* p, float a, float b, float c, float d) {
  *(float4*)p = make_float4(a, b, c, d);
}
__device__ __forceinline__ void st4(unsigned short* p, float a, float b, float c, float d) {
  ushort4 u; u.x = f2bf(a); u.y = f2bf(b); u.z = f2bf(c); u.w = f2bf(d);
  *(ushort4*)p = u;
}

// ---------------------------------------------------------------------------
// Tiled GEMM C = A @ W (fp32 accumulate). TA: float|ushort(bf16) input,
// TC: float|ushort(bf16) output. QMODE: C written head-major [b][h][s][256].
//   A row for token m: b = m/L, s = m%L -> (b*a_batch + a_off + s)*K
//   C row (std):                          (b*c_batch + c_off + s)*N
// ---------------------------------------------------------------------------
template <typename TA, typename TC, bool QMODE>
__global__ __launch_bounds__(256) void gemm_t(
    const TA* __restrict__ A, const float* __restrict__ W, TC* __restrict__ C,
    int L, int K, int N, int a_batch, int a_off, int c_batch, int c_off, int M_total)
{
  __shared__ float As[16][64];
  __shared__ float Bs[16][64];
  const int tid = threadIdx.x;
  const int bn0 = blockIdx.x * 64;
  const int bm0 = blockIdx.y * 64;

  const int a_ml = tid >> 2;
  const int a_kq = (tid & 3) << 2;
  const int mA = bm0 + a_ml;
  const bool a_valid = mA < M_total;
  int ab = 0, as = 0;
  if (a_valid) { ab = mA / L; as = mA - ab * L; }
  const TA* a_ptr = A + (size_t)(ab * a_batch + a_off + as) * K + a_kq;

  const int b_kl = tid >> 4;
  const int b_nq = (tid & 15) << 2;
  const float* b_ptr = W + (size_t)b_kl * N + bn0 + b_nq;

  const int ty = tid >> 4;
  const int tx = tid & 15;

  float acc[4][4] = {{0.f}};

  for (int k0 = 0; k0 < K; k0 += 16) {
    float4 av = make_float4(0.f, 0.f, 0.f, 0.f);
    if (a_valid) av = ld4(a_ptr + k0);
    const float4 bv = *(const float4*)(b_ptr + (size_t)k0 * N);
    As[a_kq + 0][a_ml] = av.x;
    As[a_kq + 1][a_ml] = av.y;
    As[a_kq + 2][a_ml] = av.z;
    As[a_kq + 3][a_ml] = av.w;
    *(float4*)&Bs[b_kl][b_nq] = bv;
    __syncthreads();
#pragma unroll
    for (int kk = 0; kk < 16; ++kk) {
      const float4 a4 = *(const float4*)&As[kk][ty << 2];
      const float4 b4 = *(const float4*)&Bs[kk][tx << 2];
      acc[0][0] += a4.x * b4.x; acc[0][1] += a4.x * b4.y; acc[0][2] += a4.x * b4.z; acc[0][3] += a4.x * b4.w;
      acc[1][0] += a4.y * b4.x; acc[1][1] += a4.y * b4.y; acc[1][2] += a4.y * b4.z; acc[1][3] += a4.y * b4.w;
      acc[2][0] += a4.z * b4.x; acc[2][1] += a4.z * b4.y; acc[2][2] += a4.z * b4.z; acc[2][3] += a4.z * b4.w;
      acc[3][0] += a4.w * b4.x; acc[3][1] += a4.w * b4.y; acc[3][2] += a4.w * b4.z; acc[3][3] += a4.w * b4.w;
    }
    __syncthreads();
  }

#pragma unroll
  for (int i = 0; i < 4; ++i) {
    const int m = bm0 + (ty << 2) + i;
    if (m < M_total) {
      const int cb = m / L, cs = m - cb * L;
      if constexpr (QMODE) {
        const int col = bn0 + (tx << 2);
        const int hh = col >> 8, dd = col & 255;
        TC* cp = C + (((size_t)cb * Hn + hh) * Sn + c_off + cs) * DHn + dd;
        st4(cp, acc[i][0], acc[i][1], acc[i][2], acc[i][3]);
      } else {
        TC* cp = C + (size_t)(cb * c_batch + c_off + cs) * N + bn0 + (tx << 2);
        st4(cp, acc[i][0], acc[i][1], acc[i][2], acc[i][3]);
      }
    }
  }
}

// ---------------------------------------------------------------------------
// RoPE in place on bf16 Q [b][h][s][256] and K [b][s][256].
// ---------------------------------------------------------------------------
__global__ __launch_bounds__(256) void rope_bf16(
    unsigned short* __restrict__ Qh, unsigned short* __restrict__ Kh,
    const int* __restrict__ p0, const int* __restrict__ p1, const int* __restrict__ p2)
{
  const int t = blockIdx.x, b = t >> 10, s = t & 1023;
  int p;
  if (s < 968)      p = p0[b * 968 + s];
  else if (s < 974) p = p1[b * 6 + (s - 968)];
  else              p = p2[b * 50 + (s - 974)];
  const float pf = (float)p;
  const float c0 = -0.07195578415606394f;  // -ln(10000)/128

  for (int idx = threadIdx.x; idx < 1152; idx += 256) {
    unsigned short* base; int d;
    if (idx < 1024) {
      const int h = idx >> 7; d = idx & 127;
      base = Qh + (((size_t)b * Hn + h) * Sn + s) * DHn;
    } else {
      d = idx - 1024;
      base = Kh + ((size_t)b * Sn + s) * DHn;
    }
    const float inv = __expf(c0 * (float)d);
    const float fr = pf * inv;
    float cs, sn;
    sincosf(fr, &sn, &cs);
    const float x1 = bf2f(base[d]), x2 = bf2f(base[d + 128]);
    base[d]       = f2bf(x1 * cs - x2 * sn);
    base[d + 128] = f2bf(x2 * cs + x1 * sn);
  }
}

// ---------------------------------------------------------------------------
// V transpose: [b][s][256] bf16 -> [b][256][1024] bf16
// ---------------------------------------------------------------------------
__global__ __launch_bounds__(256) void vtrans(
    const unsigned short* __restrict__ Vh, unsigned short* __restrict__ Vt)
{
  __shared__ unsigned short t[32][33];
  const int st = blockIdx.x * 32, dt = blockIdx.y * 32, b = blockIdx.z;
  const int tx = threadIdx.x & 31, ty = threadIdx.x >> 5;
  for (int i = ty; i < 32; i += 8)
    t[i][tx] = Vh[((size_t)b * Sn + st + i) * DHn + dt + tx];
  __syncthreads();
  for (int i = ty; i < 32; i += 8)
    Vt[((size_t)b * DHn + dt + i) * Sn + st + tx] = t[tx][i];
}

// ---------------------------------------------------------------------------
// MFMA flash attention. Block = (b, h, 64 q-rows), 4 waves x 16 q-rows.
// Fixed-max softmax: p = exp(score - 50); scores bounded by tanh cap.
// ---------------------------------------------------------------------------
__global__ __launch_bounds__(256) void attn_mfma(
    const unsigned short* __restrict__ Qh, const unsigned short* __restrict__ Kh,
    const unsigned short* __restrict__ Vt, const float* __restrict__ mask,
    unsigned short* __restrict__ O)
{
  __shared__ short Pb[4][16][32];   // per-wave P bounce (C-layout -> A-layout)
  const int tid = threadIdx.x;
  const int w  = tid >> 6;
  const int l  = tid & 63;
  const int lc = l & 15;            // frag col / A row
  const int lg = l >> 4;            // lane group 0..3
  const int q0 = blockIdx.x * 64;
  const int h  = blockIdx.y;
  const int b  = blockIdx.z;
  const int qr0 = q0 + w * 16;

  // Q A-frags (A row = lc), 8 d-tiles of 32
  const unsigned short* qrow = Qh + (((size_t)b * Hn + h) * Sn + qr0 + lc) * DHn;
  bf16x8 qf[8];
#pragma unroll
  for (int dt = 0; dt < 8; ++dt)
    qf[dt] = *(const bf16x8*)(qrow + dt * 32 + lg * 8);

  f32x4 accO[16];
#pragma unroll
  for (int i = 0; i < 16; ++i) accO[i] = (f32x4){0.f, 0.f, 0.f, 0.f};
  float lsum[4] = {0.f, 0.f, 0.f, 0.f};

  const unsigned short* Kb = Kh + (size_t)b * Sn * DHn;
  const unsigned short* Vb = Vt + (size_t)b * DHn * Sn;
  const float* mbase = mask + (size_t)b * Sn * Sn + (size_t)(qr0 + lg * 4) * Sn;

  for (int kt = 0; kt < 32; ++kt) {
    const int k0 = kt * 32;
    // QK^T: two 16-key column tiles, accumulate over d
    f32x4 sc[2];
#pragma unroll
    for (int ct = 0; ct < 2; ++ct) {
      f32x4 acc = (f32x4){0.f, 0.f, 0.f, 0.f};
      const unsigned short* krow = Kb + (size_t)(k0 + ct * 16 + lc) * DHn;
#pragma unroll
      for (int dt = 0; dt < 8; ++dt) {
        const bf16x8 kf = *(const bf16x8*)(krow + dt * 32 + lg * 8);
        acc = __builtin_amdgcn_mfma_f32_16x16x32_bf16(qf[dt], kf, acc, 0, 0, 0);
      }
      sc[ct] = acc;
    }
    // soft-cap + mask + exp(s-50) -> P (bf16) to LDS
#pragma unroll
    for (int ct = 0; ct < 2; ++ct) {
      const int kcol = k0 + ct * 16 + lc;
#pragma unroll
      for (int r = 0; r < 4; ++r) {
        float x = sc[ct][r] * 1.25e-3f;              // (qk/16)/50
        x = fminf(fmaxf(x, -8.f), 8.f);
        const float e2 = __expf(2.f * x);
        const float capv = 50.f * (e2 - 1.f) / (e2 + 1.f);
        const float mv = mbase[(size_t)r * Sn + kcol];
        const float pv = __expf(capv + mv - 50.f);
        lsum[r] += pv;
        Pb[w][lg * 4 + r][ct * 16 + lc] = (short)f2bf(pv);
      }
    }
    // P A-frag (row = lc, k-slice = lg*8..+7) — wave-private, no barrier
    const bf16x8 pf = *(const bf16x8*)(&Pb[w][lc][lg * 8]);
    // PV over 16 output d-tiles
#pragma unroll
    for (int nt = 0; nt < 16; ++nt) {
      const bf16x8 vf = *(const bf16x8*)(Vb + (size_t)(nt * 16 + lc) * Sn + k0 + lg * 8);
      accO[nt] = __builtin_amdgcn_mfma_f32_16x16x32_bf16(pf, vf, accO[nt], 0, 0, 0);
    }
  }

  // denominator: reduce over the 16 col-lanes
#pragma unroll
  for (int mm = 1; mm < 16; mm <<= 1) {
#pragma unroll
    for (int r = 0; r < 4; ++r) lsum[r] += __shfl_xor(lsum[r], mm);
  }
  float rinv[4];
#pragma unroll
  for (int r = 0; r < 4; ++r) rinv[r] = 1.f / lsum[r];

  unsigned short* obase = O + ((size_t)b * Sn + qr0 + lg * 4) * HDn + h * DHn + lc;
#pragma unroll
  for (int nt = 0; nt < 16; ++nt)
#pragma unroll
    for (int r = 0; r < 4; ++r)
      obase[(size_t)r * HDn + nt * 16] = f2bf(accO[nt][r] * rinv[r]);
}

// ---------------------------------------------------------------------------
extern "C" void kernel_launch(void* const* d_in, const int* in_sizes, int n_in,
                              void* d_out, int out_size, void* d_ws, size_t ws_size,
                              hipStream_t stream) {
  (void)in_sizes; (void)n_in; (void)out_size; (void)ws_size;
  const float* hs0  = (const float*)d_in[0];
  const float* hs1  = (const float*)d_in[1];
  const float* hs2  = (const float*)d_in[2];
  const float* mask = (const float*)d_in[3];
  const int*   pos0 = (const int*)d_in[4];
  const int*   pos1 = (const int*)d_in[5];
  const int*   pos2 = (const int*)d_in[6];
  const float* wq[3] = {(const float*)d_in[7],  (const float*)d_in[11], (const float*)d_in[15]};
  const float* wk[3] = {(const float*)d_in[8],  (const float*)d_in[12], (const float*)d_in[16]};
  const float* wv[3] = {(const float*)d_in[9],  (const float*)d_in[13], (const float*)d_in[17]};
  const float* wo[3] = {(const float*)d_in[10], (const float*)d_in[14], (const float*)d_in[18]};
  float* out = (float*)d_out;

  // ws (bf16): Qh [b][h][s][256] | Kh [b][s][256] | Vh [b][s][256] |
  //            Vt [b][256][s]    | Ob [b][s][2048]            (~79.7 MB)
  unsigned short* Qh = (unsigned short*)d_ws;
  unsigned short* Kh = Qh + (size_t)Bn * Sn * HDn;
  unsigned short* Vh = Kh + (size_t)Bn * Sn * DHn;
  unsigned short* Vt = Vh + (size_t)Bn * Sn * DHn;
  unsigned short* Ob = Vt + (size_t)Bn * Sn * DHn;

  const int  Ls[3]   = {968, 6, 50};
  const int  offs[3] = {0, 968, 974};
  const int  hid[3]  = {2048, 1024, 1024};
  const float* hs[3] = {hs0, hs1, hs2};

  dim3 blk(256);
  for (int g = 0; g < 3; ++g) {
    const int L = Ls[g], Kd = hid[g], off = offs[g], M = Bn * L;
    dim3 gq(HDn / 64, (M + 63) / 64);
    hipLaunchKernelGGL((gemm_t<float, unsigned short, true>), gq, blk, 0, stream,
                       hs[g], wq[g], Qh, L, Kd, HDn, L, 0, 0, off, M);
    dim3 gk(DHn / 64, (M + 63) / 64);
    hipLaunchKernelGGL((gemm_t<float, unsigned short, false>), gk, blk, 0, stream,
                       hs[g], wk[g], Kh, L, Kd, DHn, L, 0, Sn, off, M);
    hipLaunchKernelGGL((gemm_t<float, unsigned short, false>), gk, blk, 0, stream,
                       hs[g], wv[g], Vh, L, Kd, DHn, L, 0, Sn, off, M);
  }

  hipLaunchKernelGGL(rope_bf16, dim3(Bn * Sn), blk, 0, stream, Qh, Kh, pos0, pos1, pos2);
  hipLaunchKernelGGL(vtrans, dim3(Sn / 32, DHn / 32, Bn), blk, 0, stream, Vh, Vt);
  hipLaunchKernelGGL(attn_mfma, dim3(Sn / 64, Hn, Bn), blk, 0, stream, Qh, Kh, Vt, mask, Ob);

  size_t ooff = 0;
  for (int g = 0; g < 3; ++g) {
    const int L = Ls[g], N = hid[g], off = offs[g], M = Bn * L;
    dim3 go(N / 64, (M + 63) / 64);
    hipLaunchKernelGGL((gemm_t<unsigned short, float, false>), go, blk, 0, stream,
                       Ob, wo[g], out + ooff, L, HDn, N, Sn, off, L, 0, M);
    ooff += (size_t)M * N;
  }
}

// Round 4
// 1694.420 us; speedup vs baseline: 8.2568x; 2.1093x over previous
//
#include <hip/hip_runtime.h>
#include <hip/hip_bf16.h>
#include <math.h>
#include <type_traits>

namespace {
constexpr int Bn = 8, Sn = 1024, Hn = 8, DHn = 256, HDn = 2048;
}

using bf16x8 = __attribute__((ext_vector_type(8))) short;
using bf16x4 = __attribute__((ext_vector_type(4))) short;
using f32x4  = __attribute__((ext_vector_type(4))) float;

__device__ __forceinline__ float bf2f(unsigned short u) {
  unsigned int x = ((unsigned int)u) << 16;
  return __builtin_bit_cast(float, x);
}
__device__ __forceinline__ unsigned short f2bf(float f) {
  unsigned int x = __builtin_bit_cast(unsigned int, f);
  x += 0x7fff + ((x >> 16) & 1);   // RNE
  return (unsigned short)(x >> 16);
}
__device__ __forceinline__ bf16x8 pack8(const float4& u, const float4& v) {
  bf16x8 r;
  r[0] = (short)f2bf(u.x); r[1] = (short)f2bf(u.y); r[2] = (short)f2bf(u.z); r[3] = (short)f2bf(u.w);
  r[4] = (short)f2bf(v.x); r[5] = (short)f2bf(v.y); r[6] = (short)f2bf(v.z); r[7] = (short)f2bf(v.w);
  return r;
}

// ---------------------------------------------------------------------------
// bf16 MFMA GEMM: C = A @ W, fp32->bf16 conversion in staging.
// A rows are tokens: m -> b=m/L, s=m%L -> A row = b*a_batch + a_off + s.
// MODE 0: C row = b*c_batch + c_off + s          (TC elem)
// MODE 1: Q head-major: C[((b*H + col>>8)*Sn + c_off + s)*256 + (col&255)]
// MODE 2: V transposed: C[(b*256 + col)*Sn + c_off + s]
// Tile 128x128, BK=32, 4 waves (2x2) each 64x64.
// ---------------------------------------------------------------------------
template <typename TA, typename TC, int MODE>
__global__ __launch_bounds__(256) void gemm_mfma(
    const TA* __restrict__ A, const float* __restrict__ W, TC* __restrict__ C,
    int L, int K, int N, int a_batch, int a_off, int c_batch, int c_off, int M_total)
{
  __shared__ __align__(16) short As[128][56];   // [m][k] pad-56 (112B stride)
  __shared__ __align__(16) short Bs[128][56];   // [n][k] (transposed W)
  const int tid = threadIdx.x;
  const int w  = tid >> 6, l = tid & 63;
  const int wm = w >> 1,  wn = w & 1;
  const int lc = l & 15,  lg = l >> 4;
  const int bn0 = blockIdx.x * 128;
  const int bm0 = blockIdx.y * 128;

  // A staging: thread -> row am = tid>>1, k-offset ak = (tid&1)*16
  const int am = tid >> 1, ak = (tid & 1) * 16;
  int mA = bm0 + am;
  if (mA >= M_total) mA = 0;                    // clamped; stores predicated
  const int ab = mA / L, asg = mA - ab * L;
  const TA* aP = A + (size_t)(ab * a_batch + a_off + asg) * K + ak;

  // B staging: thread -> n0 = 4*(tid&31), kq = 4*(tid>>5)
  const int bn = (tid & 31) * 4, bkq = (tid >> 5) * 4;
  const float* bP = W + (size_t)bkq * N + bn0 + bn;

  f32x4 acc[4][4];
#pragma unroll
  for (int i = 0; i < 4; ++i)
#pragma unroll
    for (int j = 0; j < 4; ++j) acc[i][j] = (f32x4){0.f, 0.f, 0.f, 0.f};

  const int nk = K >> 5;

  // staging registers
  float4 aRf[4]; bf16x8 aRb[2]; float4 bR[4];

  auto loadA = [&](int k0) {
    if constexpr (std::is_same_v<TA, float>) {
#pragma unroll
      for (int i = 0; i < 4; ++i) aRf[i] = *(const float4*)(aP + k0 + i * 4);
    } else {
      aRb[0] = *(const bf16x8*)(aP + k0);
      aRb[1] = *(const bf16x8*)(aP + k0 + 8);
    }
  };
  auto loadB = [&](int k0) {
#pragma unroll
    for (int i = 0; i < 4; ++i) bR[i] = *(const float4*)(bP + (size_t)(k0 + i) * N);
  };
  auto writeA = [&]() {
    if constexpr (std::is_same_v<TA, float>) {
      *(bf16x8*)&As[am][ak]     = pack8(aRf[0], aRf[1]);
      *(bf16x8*)&As[am][ak + 8] = pack8(aRf[2], aRf[3]);
    } else {
      *(bf16x8*)&As[am][ak]     = aRb[0];
      *(bf16x8*)&As[am][ak + 8] = aRb[1];
    }
  };
  auto writeB = [&]() {
    const float* b0 = (const float*)&bR[0];
    const float* b1 = (const float*)&bR[1];
    const float* b2 = (const float*)&bR[2];
    const float* b3 = (const float*)&bR[3];
#pragma unroll
    for (int j = 0; j < 4; ++j) {
      bf16x4 v;
      v[0] = (short)f2bf(b0[j]); v[1] = (short)f2bf(b1[j]);
      v[2] = (short)f2bf(b2[j]); v[3] = (short)f2bf(b3[j]);
      *(bf16x4*)&Bs[bn + j][bkq] = v;
    }
  };

  loadA(0); loadB(0);
  for (int kt = 0; kt < nk; ++kt) {
    __syncthreads();                 // previous tile consumed
    writeA(); writeB();
    __syncthreads();                 // tile ready
    if (kt + 1 < nk) { loadA((kt + 1) * 32); loadB((kt + 1) * 32); }  // T14: issue early
    bf16x8 af[4], bfg[4];
#pragma unroll
    for (int mi = 0; mi < 4; ++mi) af[mi]  = *(const bf16x8*)&As[wm * 64 + mi * 16 + lc][lg * 8];
#pragma unroll
    for (int ni = 0; ni < 4; ++ni) bfg[ni] = *(const bf16x8*)&Bs[wn * 64 + ni * 16 + lc][lg * 8];
#pragma unroll
    for (int mi = 0; mi < 4; ++mi)
#pragma unroll
      for (int ni = 0; ni < 4; ++ni)
        acc[mi][ni] = __builtin_amdgcn_mfma_f32_16x16x32_bf16(af[mi], bfg[ni], acc[mi][ni], 0, 0, 0);
  }

  // Epilogue: C-layout row = lg*4 + r, col = lc
#pragma unroll
  for (int mi = 0; mi < 4; ++mi) {
    const int gm = bm0 + wm * 64 + mi * 16 + lg * 4;
#pragma unroll
    for (int r = 0; r < 4; ++r) {
      const int m = gm + r;
      if (m < M_total) {
        const int cb = m / L, cs = m - cb * L;
#pragma unroll
        for (int ni = 0; ni < 4; ++ni) {
          const int col = bn0 + wn * 64 + ni * 16 + lc;
          const float v = acc[mi][ni][r];
          if constexpr (MODE == 0) {
            if constexpr (std::is_same_v<TC, float>)
              C[(size_t)(cb * c_batch + c_off + cs) * N + col] = v;
            else
              C[(size_t)(cb * c_batch + c_off + cs) * N + col] = (TC)f2bf(v);
          } else if constexpr (MODE == 1) {
            const int hh = col >> 8, dd = col & 255;
            C[(((size_t)cb * Hn + hh) * Sn + c_off + cs) * DHn + dd] = (TC)f2bf(v);
          } else {
            C[((size_t)cb * DHn + col) * Sn + c_off + cs] = (TC)f2bf(v);
          }
        }
      }
    }
  }
}

// ---------------------------------------------------------------------------
// RoPE in place on bf16 Q [b][h][s][256] and K [b][s][256].
// ---------------------------------------------------------------------------
__global__ __launch_bounds__(256) void rope_bf16(
    unsigned short* __restrict__ Qh, unsigned short* __restrict__ Kh,
    const int* __restrict__ p0, const int* __restrict__ p1, const int* __restrict__ p2)
{
  const int t = blockIdx.x, b = t >> 10, s = t & 1023;
  int p;
  if (s < 968)      p = p0[b * 968 + s];
  else if (s < 974) p = p1[b * 6 + (s - 968)];
  else              p = p2[b * 50 + (s - 974)];
  const float pf = (float)p;
  const float c0 = -0.07195578415606394f;  // -ln(10000)/128

  for (int idx = threadIdx.x; idx < 1152; idx += 256) {
    unsigned short* base; int d;
    if (idx < 1024) {
      const int h = idx >> 7; d = idx & 127;
      base = Qh + (((size_t)b * Hn + h) * Sn + s) * DHn;
    } else {
      d = idx - 1024;
      base = Kh + ((size_t)b * Sn + s) * DHn;
    }
    const float inv = __expf(c0 * (float)d);
    const float fr = pf * inv;
    float cs, sn;
    sincosf(fr, &sn, &cs);
    const float x1 = bf2f(base[d]), x2 = bf2f(base[d + 128]);
    base[d]       = f2bf(x1 * cs - x2 * sn);
    base[d + 128] = f2bf(x2 * cs + x1 * sn);
  }
}

// ---------------------------------------------------------------------------
// MFMA flash attention. Block = (b, h, 64 q-rows), 4 waves x 16 q-rows.
// Fixed-max softmax: p = exp(score - 50); scores bounded by tanh cap.
// ---------------------------------------------------------------------------
__global__ __launch_bounds__(256) void attn_mfma(
    const unsigned short* __restrict__ Qh, const unsigned short* __restrict__ Kh,
    const unsigned short* __restrict__ Vt, const float* __restrict__ mask,
    unsigned short* __restrict__ O)
{
  __shared__ short Pb[4][16][32];   // per-wave P bounce (C-layout -> A-layout)
  const int tid = threadIdx.x;
  const int w  = tid >> 6;
  const int l  = tid & 63;
  const int lc = l & 15;
  const int lg = l >> 4;
  const int q0 = blockIdx.x * 64;
  const int h  = blockIdx.y;
  const int b  = blockIdx.z;
  const int qr0 = q0 + w * 16;

  const unsigned short* qrow = Qh + (((size_t)b * Hn + h) * Sn + qr0 + lc) * DHn;
  bf16x8 qf[8];
#pragma unroll
  for (int dt = 0; dt < 8; ++dt)
    qf[dt] = *(const bf16x8*)(qrow + dt * 32 + lg * 8);

  f32x4 accO[16];
#pragma unroll
  for (int i = 0; i < 16; ++i) accO[i] = (f32x4){0.f, 0.f, 0.f, 0.f};
  float lsum[4] = {0.f, 0.f, 0.f, 0.f};

  const unsigned short* Kb = Kh + (size_t)b * Sn * DHn;
  const unsigned short* Vb = Vt + (size_t)b * DHn * Sn;
  const float* mbase = mask + (size_t)b * Sn * Sn + (size_t)(qr0 + lg * 4) * Sn;

  for (int kt = 0; kt < 32; ++kt) {
    const int k0 = kt * 32;
    f32x4 sc[2];
#pragma unroll
    for (int ct = 0; ct < 2; ++ct) {
      f32x4 acc = (f32x4){0.f, 0.f, 0.f, 0.f};
      const unsigned short* krow = Kb + (size_t)(k0 + ct * 16 + lc) * DHn;
#pragma unroll
      for (int dt = 0; dt < 8; ++dt) {
        const bf16x8 kf = *(const bf16x8*)(krow + dt * 32 + lg * 8);
        acc = __builtin_amdgcn_mfma_f32_16x16x32_bf16(qf[dt], kf, acc, 0, 0, 0);
      }
      sc[ct] = acc;
    }
#pragma unroll
    for (int ct = 0; ct < 2; ++ct) {
      const int kcol = k0 + ct * 16 + lc;
#pragma unroll
      for (int r = 0; r < 4; ++r) {
        float x = sc[ct][r] * 1.25e-3f;              // (qk/16)/50
        x = fminf(fmaxf(x, -8.f), 8.f);
        const float e2 = __expf(2.f * x);
        const float capv = 50.f * (e2 - 1.f) / (e2 + 1.f);
        const float mv = mbase[(size_t)r * Sn + kcol];
        const float pv = __expf(capv + mv - 50.f);
        lsum[r] += pv;
        Pb[w][lg * 4 + r][ct * 16 + lc] = (short)f2bf(pv);
      }
    }
    const bf16x8 pf = *(const bf16x8*)(&Pb[w][lc][lg * 8]);
#pragma unroll
    for (int nt = 0; nt < 16; ++nt) {
      const bf16x8 vf = *(const bf16x8*)(Vb + (size_t)(nt * 16 + lc) * Sn + k0 + lg * 8);
      accO[nt] = __builtin_amdgcn_mfma_f32_16x16x32_bf16(pf, vf, accO[nt], 0, 0, 0);
    }
  }

#pragma unroll
  for (int mm = 1; mm < 16; mm <<= 1) {
#pragma unroll
    for (int r = 0; r < 4; ++r) lsum[r] += __shfl_xor(lsum[r], mm);
  }
  float rinv[4];
#pragma unroll
  for (int r = 0; r < 4; ++r) rinv[r] = 1.f / lsum[r];

  unsigned short* obase = O + ((size_t)b * Sn + qr0 + lg * 4) * HDn + h * DHn + lc;
#pragma unroll
  for (int nt = 0; nt < 16; ++nt)
#pragma unroll
    for (int r = 0; r < 4; ++r)
      obase[(size_t)r * HDn + nt * 16] = f2bf(accO[nt][r] * rinv[r]);
}

// ---------------------------------------------------------------------------
extern "C" void kernel_launch(void* const* d_in, const int* in_sizes, int n_in,
                              void* d_out, int out_size, void* d_ws, size_t ws_size,
                              hipStream_t stream) {
  (void)in_sizes; (void)n_in; (void)out_size; (void)ws_size;
  const float* hs0  = (const float*)d_in[0];
  const float* hs1  = (const float*)d_in[1];
  const float* hs2  = (const float*)d_in[2];
  const float* mask = (const float*)d_in[3];
  const int*   pos0 = (const int*)d_in[4];
  const int*   pos1 = (const int*)d_in[5];
  const int*   pos2 = (const int*)d_in[6];
  const float* wq[3] = {(const float*)d_in[7],  (const float*)d_in[11], (const float*)d_in[15]};
  const float* wk[3] = {(const float*)d_in[8],  (const float*)d_in[12], (const float*)d_in[16]};
  const float* wv[3] = {(const float*)d_in[9],  (const float*)d_in[13], (const float*)d_in[17]};
  const float* wo[3] = {(const float*)d_in[10], (const float*)d_in[14], (const float*)d_in[18]};
  float* out = (float*)d_out;

  // ws (bf16): Qh [b][h][s][256] | Kh [b][s][256] | Vt [b][256][s] | Ob [b][s][2048]
  unsigned short* Qh = (unsigned short*)d_ws;
  unsigned short* Kh = Qh + (size_t)Bn * Sn * HDn;
  unsigned short* Vt = Kh + (size_t)Bn * Sn * DHn;
  unsigned short* Ob = Vt + (size_t)Bn * Sn * DHn;

  const int  Ls[3]   = {968, 6, 50};
  const int  offs[3] = {0, 968, 974};
  const int  hid[3]  = {2048, 1024, 1024};
  const float* hs[3] = {hs0, hs1, hs2};

  dim3 blk(256);
  for (int g = 0; g < 3; ++g) {
    const int L = Ls[g], Kd = hid[g], off = offs[g], M = Bn * L;
    const int gy = (M + 127) / 128;
    hipLaunchKernelGGL((gemm_mfma<float, unsigned short, 1>), dim3(HDn / 128, gy), blk, 0, stream,
                       hs[g], wq[g], Qh, L, Kd, HDn, L, 0, 0, off, M);
    hipLaunchKernelGGL((gemm_mfma<float, unsigned short, 0>), dim3(DHn / 128, gy), blk, 0, stream,
                       hs[g], wk[g], Kh, L, Kd, DHn, L, 0, Sn, off, M);
    hipLaunchKernelGGL((gemm_mfma<float, unsigned short, 2>), dim3(DHn / 128, gy), blk, 0, stream,
                       hs[g], wv[g], Vt, L, Kd, DHn, L, 0, 0, off, M);
  }

  hipLaunchKernelGGL(rope_bf16, dim3(Bn * Sn), blk, 0, stream, Qh, Kh, pos0, pos1, pos2);
  hipLaunchKernelGGL(attn_mfma, dim3(Sn / 64, Hn, Bn), blk, 0, stream, Qh, Kh, Vt, mask, Ob);

  size_t ooff = 0;
  for (int g = 0; g < 3; ++g) {
    const int L = Ls[g], N = hid[g], off = offs[g], M = Bn * L;
    const int gy = (M + 127) / 128;
    hipLaunchKernelGGL((gemm_mfma<unsigned short, float, 0>), dim3(N / 128, gy), blk, 0, stream,
                       Ob, wo[g], out + ooff, L, HDn, N, Sn, off, L, 0, M);
    ooff += (size_t)M * N;
  }
}

// Round 5
// 1275.531 us; speedup vs baseline: 10.9683x; 1.3284x over previous
//
#include <hip/hip_runtime.h>
#include <hip/hip_bf16.h>
#include <math.h>
#include <type_traits>

namespace {
constexpr int Bn = 8, Sn = 1024, Hn = 8, DHn = 256, HDn = 2048;
}

using bf16x8 = __attribute__((ext_vector_type(8))) short;
using bf16x4 = __attribute__((ext_vector_type(4))) short;
using f32x4  = __attribute__((ext_vector_type(4))) float;

__device__ __forceinline__ float bf2f(unsigned short u) {
  unsigned int x = ((unsigned int)u) << 16;
  return __builtin_bit_cast(float, x);
}
__device__ __forceinline__ unsigned short f2bf(float f) {
  unsigned int x = __builtin_bit_cast(unsigned int, f);
  x += 0x7fff + ((x >> 16) & 1);   // RNE
  return (unsigned short)(x >> 16);
}
__device__ __forceinline__ bf16x8 pack8(const float4& u, const float4& v) {
  bf16x8 r;
  r[0] = (short)f2bf(u.x); r[1] = (short)f2bf(u.y); r[2] = (short)f2bf(u.z); r[3] = (short)f2bf(u.w);
  r[4] = (short)f2bf(v.x); r[5] = (short)f2bf(v.y); r[6] = (short)f2bf(v.z); r[7] = (short)f2bf(v.w);
  return r;
}
__device__ __forceinline__ void gload_lds16(const void* g, void* l) {
  __builtin_amdgcn_global_load_lds(
      (const __attribute__((address_space(1))) void*)g,
      (__attribute__((address_space(3))) void*)l, 16, 0, 0);
}

// ---------------------------------------------------------------------------
// bf16 MFMA GEMM (unchanged from round 4): C = A @ W, fp32->bf16 in staging.
// MODE 0: std rows; MODE 1: Q head-major; MODE 2: V transposed.
// ---------------------------------------------------------------------------
template <typename TA, typename TC, int MODE>
__global__ __launch_bounds__(256) void gemm_mfma(
    const TA* __restrict__ A, const float* __restrict__ W, TC* __restrict__ C,
    int L, int K, int N, int a_batch, int a_off, int c_batch, int c_off, int M_total)
{
  __shared__ __align__(16) short As[128][56];
  __shared__ __align__(16) short Bs[128][56];
  const int tid = threadIdx.x;
  const int w  = tid >> 6, l = tid & 63;
  const int wm = w >> 1,  wn = w & 1;
  const int lc = l & 15,  lg = l >> 4;
  const int bn0 = blockIdx.x * 128;
  const int bm0 = blockIdx.y * 128;

  const int am = tid >> 1, ak = (tid & 1) * 16;
  int mA = bm0 + am;
  if (mA >= M_total) mA = 0;
  const int ab = mA / L, asg = mA - ab * L;
  const TA* aP = A + (size_t)(ab * a_batch + a_off + asg) * K + ak;

  const int bn = (tid & 31) * 4, bkq = (tid >> 5) * 4;
  const float* bP = W + (size_t)bkq * N + bn0 + bn;

  f32x4 acc[4][4];
#pragma unroll
  for (int i = 0; i < 4; ++i)
#pragma unroll
    for (int j = 0; j < 4; ++j) acc[i][j] = (f32x4){0.f, 0.f, 0.f, 0.f};

  const int nk = K >> 5;
  float4 aRf[4]; bf16x8 aRb[2]; float4 bR[4];

  auto loadA = [&](int k0) {
    if constexpr (std::is_same_v<TA, float>) {
#pragma unroll
      for (int i = 0; i < 4; ++i) aRf[i] = *(const float4*)(aP + k0 + i * 4);
    } else {
      aRb[0] = *(const bf16x8*)(aP + k0);
      aRb[1] = *(const bf16x8*)(aP + k0 + 8);
    }
  };
  auto loadB = [&](int k0) {
#pragma unroll
    for (int i = 0; i < 4; ++i) bR[i] = *(const float4*)(bP + (size_t)(k0 + i) * N);
  };
  auto writeA = [&]() {
    if constexpr (std::is_same_v<TA, float>) {
      *(bf16x8*)&As[am][ak]     = pack8(aRf[0], aRf[1]);
      *(bf16x8*)&As[am][ak + 8] = pack8(aRf[2], aRf[3]);
    } else {
      *(bf16x8*)&As[am][ak]     = aRb[0];
      *(bf16x8*)&As[am][ak + 8] = aRb[1];
    }
  };
  auto writeB = [&]() {
    const float* b0 = (const float*)&bR[0];
    const float* b1 = (const float*)&bR[1];
    const float* b2 = (const float*)&bR[2];
    const float* b3 = (const float*)&bR[3];
#pragma unroll
    for (int j = 0; j < 4; ++j) {
      bf16x4 v;
      v[0] = (short)f2bf(b0[j]); v[1] = (short)f2bf(b1[j]);
      v[2] = (short)f2bf(b2[j]); v[3] = (short)f2bf(b3[j]);
      *(bf16x4*)&Bs[bn + j][bkq] = v;
    }
  };

  loadA(0); loadB(0);
  for (int kt = 0; kt < nk; ++kt) {
    __syncthreads();
    writeA(); writeB();
    __syncthreads();
    if (kt + 1 < nk) { loadA((kt + 1) * 32); loadB((kt + 1) * 32); }
    bf16x8 af[4], bfg[4];
#pragma unroll
    for (int mi = 0; mi < 4; ++mi) af[mi]  = *(const bf16x8*)&As[wm * 64 + mi * 16 + lc][lg * 8];
#pragma unroll
    for (int ni = 0; ni < 4; ++ni) bfg[ni] = *(const bf16x8*)&Bs[wn * 64 + ni * 16 + lc][lg * 8];
#pragma unroll
    for (int mi = 0; mi < 4; ++mi)
#pragma unroll
      for (int ni = 0; ni < 4; ++ni)
        acc[mi][ni] = __builtin_amdgcn_mfma_f32_16x16x32_bf16(af[mi], bfg[ni], acc[mi][ni], 0, 0, 0);
  }

#pragma unroll
  for (int mi = 0; mi < 4; ++mi) {
    const int gm = bm0 + wm * 64 + mi * 16 + lg * 4;
#pragma unroll
    for (int r = 0; r < 4; ++r) {
      const int m = gm + r;
      if (m < M_total) {
        const int cb = m / L, cs = m - cb * L;
#pragma unroll
        for (int ni = 0; ni < 4; ++ni) {
          const int col = bn0 + wn * 64 + ni * 16 + lc;
          const float v = acc[mi][ni][r];
          if constexpr (MODE == 0) {
            if constexpr (std::is_same_v<TC, float>)
              C[(size_t)(cb * c_batch + c_off + cs) * N + col] = v;
            else
              C[(size_t)(cb * c_batch + c_off + cs) * N + col] = (TC)f2bf(v);
          } else if constexpr (MODE == 1) {
            const int hh = col >> 8, dd = col & 255;
            C[(((size_t)cb * Hn + hh) * Sn + c_off + cs) * DHn + dd] = (TC)f2bf(v);
          } else {
            C[((size_t)cb * DHn + col) * Sn + c_off + cs] = (TC)f2bf(v);
          }
        }
      }
    }
  }
}

// ---------------------------------------------------------------------------
// RoPE in place on bf16 Q [b][h][s][256] and K [b][s][256].
// ---------------------------------------------------------------------------
__global__ __launch_bounds__(256) void rope_bf16(
    unsigned short* __restrict__ Qh, unsigned short* __restrict__ Kh,
    const int* __restrict__ p0, const int* __restrict__ p1, const int* __restrict__ p2)
{
  const int t = blockIdx.x, b = t >> 10, s = t & 1023;
  int p;
  if (s < 968)      p = p0[b * 968 + s];
  else if (s < 974) p = p1[b * 6 + (s - 968)];
  else              p = p2[b * 50 + (s - 974)];
  const float pf = (float)p;
  const float c0 = -0.07195578415606394f;

  for (int idx = threadIdx.x; idx < 1152; idx += 256) {
    unsigned short* base; int d;
    if (idx < 1024) {
      const int h = idx >> 7; d = idx & 127;
      base = Qh + (((size_t)b * Hn + h) * Sn + s) * DHn;
    } else {
      d = idx - 1024;
      base = Kh + ((size_t)b * Sn + s) * DHn;
    }
    const float inv = __expf(c0 * (float)d);
    const float fr = pf * inv;
    float cs, sn;
    sincosf(fr, &sn, &cs);
    const float x1 = bf2f(base[d]), x2 = bf2f(base[d + 128]);
    base[d]       = f2bf(x1 * cs - x2 * sn);
    base[d + 128] = f2bf(x2 * cs + x1 * sn);
  }
}

// ---------------------------------------------------------------------------
// MFMA flash attention v2. Block = (b, h, 64 q-rows), 4 waves x 16 q-rows.
// K/V tiles (32 keys) double-buffered in LDS via global_load_lds, swizzled;
// mask register-prefetched one tile ahead; counted vmcnt(16) + raw barriers.
// ---------------------------------------------------------------------------
__global__ __launch_bounds__(256) void attn_mfma(
    const unsigned short* __restrict__ Qh, const unsigned short* __restrict__ Kh,
    const unsigned short* __restrict__ Vt, const float* __restrict__ mask,
    unsigned short* __restrict__ O)
{
  // K tile: 32 rows x 256 d (512B rows), psi_K(o) = o ^ (((o>>9)&7)<<4)
  // V tile: 256 rows x 32 k  (64B rows), psi_V(o) = o ^ (((o>>7)&3)<<4)
  __shared__ __align__(16) short KsB[2][16384 / 2];
  __shared__ __align__(16) short VsB[2][16384 / 2];
  __shared__ short Pb[4][16][32];
  const int tid = threadIdx.x;
  const int w  = tid >> 6;
  const int l  = tid & 63;
  const int lc = l & 15;
  const int lg = l >> 4;
  const int q0 = blockIdx.x * 64;
  const int h  = blockIdx.y;
  const int b  = blockIdx.z;
  const int qr0 = q0 + w * 16;

  const unsigned short* qrow = Qh + (((size_t)b * Hn + h) * Sn + qr0 + lc) * DHn;
  bf16x8 qf[8];
#pragma unroll
  for (int dt = 0; dt < 8; ++dt)
    qf[dt] = *(const bf16x8*)(qrow + dt * 32 + lg * 8);

  f32x4 accO[16];
#pragma unroll
  for (int i = 0; i < 16; ++i) accO[i] = (f32x4){0.f, 0.f, 0.f, 0.f};
  float lsum[4] = {0.f, 0.f, 0.f, 0.f};

  const char* KgB = (const char*)(Kh + (size_t)b * Sn * DHn);   // byte base
  const char* VgB = (const char*)(Vt + (size_t)b * DHn * Sn);
  const float* mbase = mask + (size_t)b * Sn * Sn + (size_t)(qr0 + lg * 4) * Sn;

  // stage tile kt into buffer nb (per-wave: 4 K-chunks + 4 V-chunks of 1 KB)
  auto stage = [&](int kt, int nb) {
    const char* kg = KgB + (size_t)kt * 32 * 512;          // contiguous 16 KB
    const char* vg = VgB + (size_t)kt * 64;                // + row*2048 + col
#pragma unroll
    for (int j = 0; j < 4; ++j) {
      const int chunk = w * 4 + j;
      const int o = chunk * 1024 + l * 16;
      const int srcK = o ^ (((o >> 9) & 7) << 4);
      gload_lds16(kg + srcK, (char*)&KsB[nb][0] + chunk * 1024);
    }
#pragma unroll
    for (int j = 0; j < 4; ++j) {
      const int chunk = w * 4 + j;
      const int o = chunk * 1024 + l * 16;
      const int x = o ^ (((o >> 7) & 3) << 4);
      gload_lds16(vg + (size_t)(x >> 6) * 2048 + (x & 63),
                  (char*)&VsB[nb][0] + chunk * 1024);
    }
  };

  float mcur[8], mnxt[8];
  stage(0, 0);
#pragma unroll
  for (int ct = 0; ct < 2; ++ct)
#pragma unroll
    for (int r = 0; r < 4; ++r)
      mcur[ct * 4 + r] = mbase[(size_t)r * Sn + ct * 16 + lc];

  int cur = 0;
  for (int kt = 0; kt < 32; ++kt) {
    const bool has_next = (kt + 1) < 32;
    if (has_next) {
      stage(kt + 1, cur ^ 1);
      const int k0n = (kt + 1) * 32;
#pragma unroll
      for (int ct = 0; ct < 2; ++ct)
#pragma unroll
        for (int r = 0; r < 4; ++r)
          mnxt[ct * 4 + r] = mbase[(size_t)r * Sn + k0n + ct * 16 + lc];
      asm volatile("s_waitcnt vmcnt(16)" ::: "memory");
    } else {
      asm volatile("s_waitcnt vmcnt(0)" ::: "memory");
    }
    __builtin_amdgcn_s_barrier();
    __builtin_amdgcn_sched_barrier(0);

    const short* Ks = &KsB[cur][0];
    const short* Vs = &VsB[cur][0];

    // QK^T from swizzled K LDS
    f32x4 sc[2];
    __builtin_amdgcn_s_setprio(1);
#pragma unroll
    for (int ct = 0; ct < 2; ++ct) {
      f32x4 acc = (f32x4){0.f, 0.f, 0.f, 0.f};
      const int row = ct * 16 + lc;
      const int sw = (row & 7) << 4;
#pragma unroll
      for (int dt = 0; dt < 8; ++dt) {
        const int byt = (row * 512 + dt * 64 + lg * 16) ^ sw;
        const bf16x8 kf = *(const bf16x8*)((const char*)Ks + byt);
        acc = __builtin_amdgcn_mfma_f32_16x16x32_bf16(qf[dt], kf, acc, 0, 0, 0);
      }
      sc[ct] = acc;
    }
    __builtin_amdgcn_s_setprio(0);

    // soft-cap + mask + exp(s-50) -> P (bf16) to wave-private LDS
#pragma unroll
    for (int ct = 0; ct < 2; ++ct) {
#pragma unroll
      for (int r = 0; r < 4; ++r) {
        float x = sc[ct][r] * 1.25e-3f;
        x = fminf(fmaxf(x, -8.f), 8.f);
        const float e2 = __expf(2.f * x);
        const float capv = 50.f * (e2 - 1.f) / (e2 + 1.f);
        const float pv = __expf(capv + mcur[ct * 4 + r] - 50.f);
        lsum[r] += pv;
        Pb[w][lg * 4 + r][ct * 16 + lc] = (short)f2bf(pv);
      }
    }
    const bf16x8 pf = *(const bf16x8*)(&Pb[w][lc][lg * 8]);

    // PV from swizzled V LDS
    __builtin_amdgcn_s_setprio(1);
#pragma unroll
    for (int nt = 0; nt < 16; ++nt) {
      const int row = nt * 16 + lc;
      const int byt = (row * 64 + lg * 16) ^ (((row >> 1) & 3) << 4);
      const bf16x8 vf = *(const bf16x8*)((const char*)Vs + byt);
      accO[nt] = __builtin_amdgcn_mfma_f32_16x16x32_bf16(pf, vf, accO[nt], 0, 0, 0);
    }
    __builtin_amdgcn_s_setprio(0);

    __builtin_amdgcn_s_barrier();   // all reads of buf[cur] done before restage
#pragma unroll
    for (int i = 0; i < 8; ++i) mcur[i] = mnxt[i];
    cur ^= 1;
  }

#pragma unroll
  for (int mm = 1; mm < 16; mm <<= 1) {
#pragma unroll
    for (int r = 0; r < 4; ++r) lsum[r] += __shfl_xor(lsum[r], mm);
  }
  float rinv[4];
#pragma unroll
  for (int r = 0; r < 4; ++r) rinv[r] = 1.f / lsum[r];

  unsigned short* obase = O + ((size_t)b * Sn + qr0 + lg * 4) * HDn + h * DHn + lc;
#pragma unroll
  for (int nt = 0; nt < 16; ++nt)
#pragma unroll
    for (int r = 0; r < 4; ++r)
      obase[(size_t)r * HDn + nt * 16] = f2bf(accO[nt][r] * rinv[r]);
}

// ---------------------------------------------------------------------------
extern "C" void kernel_launch(void* const* d_in, const int* in_sizes, int n_in,
                              void* d_out, int out_size, void* d_ws, size_t ws_size,
                              hipStream_t stream) {
  (void)in_sizes; (void)n_in; (void)out_size; (void)ws_size;
  const float* hs0  = (const float*)d_in[0];
  const float* hs1  = (const float*)d_in[1];
  const float* hs2  = (const float*)d_in[2];
  const float* mask = (const float*)d_in[3];
  const int*   pos0 = (const int*)d_in[4];
  const int*   pos1 = (const int*)d_in[5];
  const int*   pos2 = (const int*)d_in[6];
  const float* wq[3] = {(const float*)d_in[7],  (const float*)d_in[11], (const float*)d_in[15]};
  const float* wk[3] = {(const float*)d_in[8],  (const float*)d_in[12], (const float*)d_in[16]};
  const float* wv[3] = {(const float*)d_in[9],  (const float*)d_in[13], (const float*)d_in[17]};
  const float* wo[3] = {(const float*)d_in[10], (const float*)d_in[14], (const float*)d_in[18]};
  float* out = (float*)d_out;

  unsigned short* Qh = (unsigned short*)d_ws;
  unsigned short* Kh = Qh + (size_t)Bn * Sn * HDn;
  unsigned short* Vt = Kh + (size_t)Bn * Sn * DHn;
  unsigned short* Ob = Vt + (size_t)Bn * Sn * DHn;

  const int  Ls[3]   = {968, 6, 50};
  const int  offs[3] = {0, 968, 974};
  const int  hid[3]  = {2048, 1024, 1024};
  const float* hs[3] = {hs0, hs1, hs2};

  dim3 blk(256);
  for (int g = 0; g < 3; ++g) {
    const int L = Ls[g], Kd = hid[g], off = offs[g], M = Bn * L;
    const int gy = (M + 127) / 128;
    hipLaunchKernelGGL((gemm_mfma<float, unsigned short, 1>), dim3(HDn / 128, gy), blk, 0, stream,
                       hs[g], wq[g], Qh, L, Kd, HDn, L, 0, 0, off, M);
    hipLaunchKernelGGL((gemm_mfma<float, unsigned short, 0>), dim3(DHn / 128, gy), blk, 0, stream,
                       hs[g], wk[g], Kh, L, Kd, DHn, L, 0, Sn, off, M);
    hipLaunchKernelGGL((gemm_mfma<float, unsigned short, 2>), dim3(DHn / 128, gy), blk, 0, stream,
                       hs[g], wv[g], Vt, L, Kd, DHn, L, 0, 0, off, M);
  }

  hipLaunchKernelGGL(rope_bf16, dim3(Bn * Sn), blk, 0, stream, Qh, Kh, pos0, pos1, pos2);
  hipLaunchKernelGGL(attn_mfma, dim3(Sn / 64, Hn, Bn), blk, 0, stream, Qh, Kh, Vt, mask, Ob);

  size_t ooff = 0;
  for (int g = 0; g < 3; ++g) {
    const int L = Ls[g], N = hid[g], off = offs[g], M = Bn * L;
    const int gy = (M + 127) / 128;
    hipLaunchKernelGGL((gemm_mfma<unsigned short, float, 0>), dim3(N / 128, gy), blk, 0, stream,
                       Ob, wo[g], out + ooff, L, HDn, N, Sn, off, L, 0, M);
    ooff += (size_t)M * N;
  }
}

// Round 6
// 802.305 us; speedup vs baseline: 17.4378x; 1.5898x over previous
//
#include <hip/hip_runtime.h>
#include <hip/hip_bf16.h>
#include <math.h>
#include <type_traits>

namespace {
constexpr int Bn = 8, Sn = 1024, Hn = 8, DHn = 256, HDn = 2048;
}

using bf16x8 = __attribute__((ext_vector_type(8))) short;
using bf16x4 = __attribute__((ext_vector_type(4))) short;
using f32x4  = __attribute__((ext_vector_type(4))) float;

__device__ __forceinline__ float bf2f(unsigned short u) {
  unsigned int x = ((unsigned int)u) << 16;
  return __builtin_bit_cast(float, x);
}
__device__ __forceinline__ unsigned short f2bf(float f) {
  unsigned int x = __builtin_bit_cast(unsigned int, f);
  x += 0x7fff + ((x >> 16) & 1);   // RNE
  return (unsigned short)(x >> 16);
}
__device__ __forceinline__ bf16x8 pack8(const float4& u, const float4& v) {
  bf16x8 r;
  r[0] = (short)f2bf(u.x); r[1] = (short)f2bf(u.y); r[2] = (short)f2bf(u.z); r[3] = (short)f2bf(u.w);
  r[4] = (short)f2bf(v.x); r[5] = (short)f2bf(v.y); r[6] = (short)f2bf(v.z); r[7] = (short)f2bf(v.w);
  return r;
}
__device__ __forceinline__ void gload_lds16(const void* g, void* l) {
  __builtin_amdgcn_global_load_lds(
      (const __attribute__((address_space(1))) void*)g,
      (__attribute__((address_space(3))) void*)l, 16, 0, 0);
}

// ---------------------------------------------------------------------------
// Merged QKV projection for one segment: one launch, N-space = 2560 cols.
// blockIdx.x <16: Q (head-major out), 16-17: K (std), 18-19: V (transposed).
// A = hs [b][L][K] fp32.  Tile 128x128, BK=32, 4 waves.
// ---------------------------------------------------------------------------
__global__ __launch_bounds__(256) void gemm_qkv(
    const float* __restrict__ A,
    const float* __restrict__ Wq, const float* __restrict__ Wk, const float* __restrict__ Wv,
    unsigned short* __restrict__ Qh, unsigned short* __restrict__ Kh, unsigned short* __restrict__ Vt,
    int L, int K, int c_off, int M_total)
{
  __shared__ __align__(16) short As[128][56];
  __shared__ __align__(16) short Bs[128][56];
  const int tid = threadIdx.x;
  const int w  = tid >> 6, l = tid & 63;
  const int wm = w >> 1,  wn = w & 1;
  const int lc = l & 15,  lg = l >> 4;
  const int bx  = blockIdx.x;
  const int bm0 = blockIdx.y * 128;

  int region, nstr, cb0;
  if (bx < 16)      { region = 0; nstr = HDn; cb0 = bx * 128; }
  else if (bx < 18) { region = 1; nstr = DHn; cb0 = bx * 128 - 2048; }
  else              { region = 2; nstr = DHn; cb0 = bx * 128 - 2304; }
  const float* W = (region == 0) ? Wq : (region == 1 ? Wk : Wv);

  const int am = tid >> 1, ak = (tid & 1) * 16;
  int mA = bm0 + am;
  if (mA >= M_total) mA = 0;
  const int ab = mA / L, asg = mA - ab * L;
  const float* aP = A + (size_t)(ab * L + asg) * K + ak;

  const int bn = (tid & 31) * 4, bkq = (tid >> 5) * 4;
  const float* bP = W + (size_t)bkq * nstr + cb0 + bn;

  f32x4 acc[4][4];
#pragma unroll
  for (int i = 0; i < 4; ++i)
#pragma unroll
    for (int j = 0; j < 4; ++j) acc[i][j] = (f32x4){0.f, 0.f, 0.f, 0.f};

  const int nk = K >> 5;
  float4 aRf[4]; float4 bR[4];

  auto loadA = [&](int k0) {
#pragma unroll
    for (int i = 0; i < 4; ++i) aRf[i] = *(const float4*)(aP + k0 + i * 4);
  };
  auto loadB = [&](int k0) {
#pragma unroll
    for (int i = 0; i < 4; ++i) bR[i] = *(const float4*)(bP + (size_t)(k0 + i) * nstr);
  };
  auto writeA = [&]() {
    *(bf16x8*)&As[am][ak]     = pack8(aRf[0], aRf[1]);
    *(bf16x8*)&As[am][ak + 8] = pack8(aRf[2], aRf[3]);
  };
  auto writeB = [&]() {
    const float* b0 = (const float*)&bR[0];
    const float* b1 = (const float*)&bR[1];
    const float* b2 = (const float*)&bR[2];
    const float* b3 = (const float*)&bR[3];
#pragma unroll
    for (int j = 0; j < 4; ++j) {
      bf16x4 v;
      v[0] = (short)f2bf(b0[j]); v[1] = (short)f2bf(b1[j]);
      v[2] = (short)f2bf(b2[j]); v[3] = (short)f2bf(b3[j]);
      *(bf16x4*)&Bs[bn + j][bkq] = v;
    }
  };

  loadA(0); loadB(0);
  for (int kt = 0; kt < nk; ++kt) {
    __syncthreads();
    writeA(); writeB();
    __syncthreads();
    if (kt + 1 < nk) { loadA((kt + 1) * 32); loadB((kt + 1) * 32); }
    bf16x8 af[4], bfg[4];
#pragma unroll
    for (int mi = 0; mi < 4; ++mi) af[mi]  = *(const bf16x8*)&As[wm * 64 + mi * 16 + lc][lg * 8];
#pragma unroll
    for (int ni = 0; ni < 4; ++ni) bfg[ni] = *(const bf16x8*)&Bs[wn * 64 + ni * 16 + lc][lg * 8];
#pragma unroll
    for (int mi = 0; mi < 4; ++mi)
#pragma unroll
      for (int ni = 0; ni < 4; ++ni)
        acc[mi][ni] = __builtin_amdgcn_mfma_f32_16x16x32_bf16(af[mi], bfg[ni], acc[mi][ni], 0, 0, 0);
  }

#pragma unroll
  for (int mi = 0; mi < 4; ++mi) {
    const int gm = bm0 + wm * 64 + mi * 16 + lg * 4;
#pragma unroll
    for (int r = 0; r < 4; ++r) {
      const int m = gm + r;
      if (m < M_total) {
        const int cb = m / L, cs = m - cb * L;
#pragma unroll
        for (int ni = 0; ni < 4; ++ni) {
          const int colL = cb0 + wn * 64 + ni * 16 + lc;
          const unsigned short v = f2bf(acc[mi][ni][r]);
          if (region == 0) {
            const int hh = colL >> 8, dd = colL & 255;
            Qh[(((size_t)cb * Hn + hh) * Sn + c_off + cs) * DHn + dd] = v;
          } else if (region == 1) {
            Kh[((size_t)cb * Sn + c_off + cs) * DHn + colL] = v;
          } else {
            Vt[((size_t)cb * DHn + colL) * Sn + c_off + cs] = v;
          }
        }
      }
    }
  }
}

// ---------------------------------------------------------------------------
// bf16 MFMA GEMM for output projections (unchanged structure).
// ---------------------------------------------------------------------------
__global__ __launch_bounds__(256) void gemm_wo(
    const unsigned short* __restrict__ A, const float* __restrict__ W, float* __restrict__ C,
    int L, int K, int N, int a_batch, int a_off, int M_total)
{
  __shared__ __align__(16) short As[128][56];
  __shared__ __align__(16) short Bs[128][56];
  const int tid = threadIdx.x;
  const int w  = tid >> 6, l = tid & 63;
  const int wm = w >> 1,  wn = w & 1;
  const int lc = l & 15,  lg = l >> 4;
  const int bn0 = blockIdx.x * 128;
  const int bm0 = blockIdx.y * 128;

  const int am = tid >> 1, ak = (tid & 1) * 16;
  int mA = bm0 + am;
  if (mA >= M_total) mA = 0;
  const int ab = mA / L, asg = mA - ab * L;
  const unsigned short* aP = A + (size_t)(ab * a_batch + a_off + asg) * K + ak;

  const int bn = (tid & 31) * 4, bkq = (tid >> 5) * 4;
  const float* bP = W + (size_t)bkq * N + bn0 + bn;

  f32x4 acc[4][4];
#pragma unroll
  for (int i = 0; i < 4; ++i)
#pragma unroll
    for (int j = 0; j < 4; ++j) acc[i][j] = (f32x4){0.f, 0.f, 0.f, 0.f};

  const int nk = K >> 5;
  bf16x8 aRb[2]; float4 bR[4];

  auto loadA = [&](int k0) {
    aRb[0] = *(const bf16x8*)(aP + k0);
    aRb[1] = *(const bf16x8*)(aP + k0 + 8);
  };
  auto loadB = [&](int k0) {
#pragma unroll
    for (int i = 0; i < 4; ++i) bR[i] = *(const float4*)(bP + (size_t)(k0 + i) * N);
  };
  auto writeA = [&]() {
    *(bf16x8*)&As[am][ak]     = aRb[0];
    *(bf16x8*)&As[am][ak + 8] = aRb[1];
  };
  auto writeB = [&]() {
    const float* b0 = (const float*)&bR[0];
    const float* b1 = (const float*)&bR[1];
    const float* b2 = (const float*)&bR[2];
    const float* b3 = (const float*)&bR[3];
#pragma unroll
    for (int j = 0; j < 4; ++j) {
      bf16x4 v;
      v[0] = (short)f2bf(b0[j]); v[1] = (short)f2bf(b1[j]);
      v[2] = (short)f2bf(b2[j]); v[3] = (short)f2bf(b3[j]);
      *(bf16x4*)&Bs[bn + j][bkq] = v;
    }
  };

  loadA(0); loadB(0);
  for (int kt = 0; kt < nk; ++kt) {
    __syncthreads();
    writeA(); writeB();
    __syncthreads();
    if (kt + 1 < nk) { loadA((kt + 1) * 32); loadB((kt + 1) * 32); }
    bf16x8 af[4], bfg[4];
#pragma unroll
    for (int mi = 0; mi < 4; ++mi) af[mi]  = *(const bf16x8*)&As[wm * 64 + mi * 16 + lc][lg * 8];
#pragma unroll
    for (int ni = 0; ni < 4; ++ni) bfg[ni] = *(const bf16x8*)&Bs[wn * 64 + ni * 16 + lc][lg * 8];
#pragma unroll
    for (int mi = 0; mi < 4; ++mi)
#pragma unroll
      for (int ni = 0; ni < 4; ++ni)
        acc[mi][ni] = __builtin_amdgcn_mfma_f32_16x16x32_bf16(af[mi], bfg[ni], acc[mi][ni], 0, 0, 0);
  }

#pragma unroll
  for (int mi = 0; mi < 4; ++mi) {
    const int gm = bm0 + wm * 64 + mi * 16 + lg * 4;
#pragma unroll
    for (int r = 0; r < 4; ++r) {
      const int m = gm + r;
      if (m < M_total) {
        const int cb = m / L, cs = m - cb * L;
#pragma unroll
        for (int ni = 0; ni < 4; ++ni) {
          const int col = bn0 + wn * 64 + ni * 16 + lc;
          C[(size_t)(cb * L + cs) * N + col] = acc[mi][ni][r];
        }
      }
    }
  }
}

// ---------------------------------------------------------------------------
// RoPE in place on bf16 K [b][s][256] only (Q rope fused into attention).
// ---------------------------------------------------------------------------
__global__ __launch_bounds__(128) void rope_k(
    unsigned short* __restrict__ Kh,
    const int* __restrict__ p0, const int* __restrict__ p1, const int* __restrict__ p2)
{
  const int t = blockIdx.x, b = t >> 10, s = t & 1023;
  int p;
  if (s < 968)      p = p0[b * 968 + s];
  else if (s < 974) p = p1[b * 6 + (s - 968)];
  else              p = p2[b * 50 + (s - 974)];
  const float pf = (float)p;
  const float c0 = -0.07195578415606394f;  // -ln(10000)/128
  const int d = threadIdx.x;               // 0..127
  const float inv = __expf(c0 * (float)d);
  float cs, sn;
  sincosf(pf * inv, &sn, &cs);
  unsigned short* base = Kh + ((size_t)b * Sn + s) * DHn;
  const float x1 = bf2f(base[d]), x2 = bf2f(base[d + 128]);
  base[d]       = f2bf(x1 * cs - x2 * sn);
  base[d + 128] = f2bf(x2 * cs + x1 * sn);
}

// ---------------------------------------------------------------------------
// MFMA flash attention v3. Block = (b, h, 128 q-rows), 8 waves x 16 rows.
// RoPE fused into Q-load. K/V LDS double-buffered (global_load_lds, swizzled),
// counted vmcnt(4); mask loaded JIT (overlaps MFMA). Fixed-max softmax.
// ---------------------------------------------------------------------------
__global__ __launch_bounds__(512) void attn_mfma(
    const unsigned short* __restrict__ Qh, const unsigned short* __restrict__ Kh,
    const unsigned short* __restrict__ Vt, const float* __restrict__ mask,
    const int* __restrict__ p0, const int* __restrict__ p1, const int* __restrict__ p2,
    unsigned short* __restrict__ O)
{
  // K tile: 32 rows x 512B, psi_K(o)=o^(((o>>9)&7)<<4)
  // V tile: 256 rows x 64B,  psi_V(o)=o^(((o>>7)&3)<<4)
  __shared__ __align__(16) short KsB[2][8192];
  __shared__ __align__(16) short VsB[2][8192];
  __shared__ short Pb[8][16][32];
  const int tid = threadIdx.x;
  const int w  = tid >> 6;
  const int l  = tid & 63;
  const int lc = l & 15;
  const int lg = l >> 4;
  const int q0 = blockIdx.x * 128;
  const int h  = blockIdx.y;
  const int b  = blockIdx.z;
  const int qr0 = q0 + w * 16;
  const int srow = qr0 + lc;

  // ---- Q load + fused RoPE ----
  int p;
  if (srow < 968)      p = p0[b * 968 + srow];
  else if (srow < 974) p = p1[b * 6 + (srow - 968)];
  else                 p = p2[b * 50 + (srow - 974)];
  const float pf = (float)p;
  const float c0 = -0.07195578415606394f;

  const unsigned short* qrow = Qh + (((size_t)b * Hn + h) * Sn + srow) * DHn;
  bf16x8 qf[8];
#pragma unroll
  for (int dt = 0; dt < 8; ++dt)
    qf[dt] = *(const bf16x8*)(qrow + dt * 32 + lg * 8);
#pragma unroll
  for (int dt = 0; dt < 4; ++dt) {
#pragma unroll
    for (int j = 0; j < 8; ++j) {
      const int d = dt * 32 + lg * 8 + j;
      const float inv = __expf(c0 * (float)d);
      float cs, sn;
      sincosf(pf * inv, &sn, &cs);
      const float x1 = bf2f((unsigned short)qf[dt][j]);
      const float x2 = bf2f((unsigned short)qf[dt + 4][j]);
      qf[dt][j]     = (short)f2bf(x1 * cs - x2 * sn);
      qf[dt + 4][j] = (short)f2bf(x2 * cs + x1 * sn);
    }
  }

  f32x4 accO[16];
#pragma unroll
  for (int i = 0; i < 16; ++i) accO[i] = (f32x4){0.f, 0.f, 0.f, 0.f};
  float lsum[4] = {0.f, 0.f, 0.f, 0.f};

  const char* KgB = (const char*)(Kh + (size_t)b * Sn * DHn);
  const char* VgB = (const char*)(Vt + (size_t)b * DHn * Sn);
  const float* mbase = mask + (size_t)b * Sn * Sn + (size_t)(qr0 + lg * 4) * Sn;

  // per-wave: 2 K-chunks + 2 V-chunks of 1 KB
  auto stage = [&](int kt, int nb) {
    const char* kg = KgB + (size_t)kt * 16384;
    const char* vg = VgB + (size_t)kt * 64;
#pragma unroll
    for (int j = 0; j < 2; ++j) {
      const int chunk = w * 2 + j;
      const int o = chunk * 1024 + l * 16;
      const int srcK = o ^ (((o >> 9) & 7) << 4);
      gload_lds16(kg + srcK, (char*)&KsB[nb][0] + chunk * 1024);
    }
#pragma unroll
    for (int j = 0; j < 2; ++j) {
      const int chunk = w * 2 + j;
      const int o = chunk * 1024 + l * 16;
      const int x = o ^ (((o >> 7) & 3) << 4);
      gload_lds16(vg + (size_t)(x >> 6) * 2048 + (x & 63),
                  (char*)&VsB[nb][0] + chunk * 1024);
    }
  };

  stage(0, 0);
  int cur = 0;
  for (int kt = 0; kt < 32; ++kt) {
    const int k0 = kt * 32;
    if (kt + 1 < 32) {
      stage(kt + 1, cur ^ 1);
      asm volatile("s_waitcnt vmcnt(4)" ::: "memory");
    } else {
      asm volatile("s_waitcnt vmcnt(0)" ::: "memory");
    }
    __builtin_amdgcn_s_barrier();
    __builtin_amdgcn_sched_barrier(0);

    const short* Ks = &KsB[cur][0];
    const short* Vs = &VsB[cur][0];

    // mask JIT loads (issue before MFMA cluster; consumed after)
    float mv[8];
#pragma unroll
    for (int ct = 0; ct < 2; ++ct)
#pragma unroll
      for (int r = 0; r < 4; ++r)
        mv[ct * 4 + r] = mbase[(size_t)r * Sn + k0 + ct * 16 + lc];

    // QK^T from swizzled K LDS
    f32x4 sc[2];
    __builtin_amdgcn_s_setprio(1);
#pragma unroll
    for (int ct = 0; ct < 2; ++ct) {
      f32x4 acc = (f32x4){0.f, 0.f, 0.f, 0.f};
      const int row = ct * 16 + lc;
      const int sw = (row & 7) << 4;
#pragma unroll
      for (int dt = 0; dt < 8; ++dt) {
        const int byt = (row * 512 + dt * 64 + lg * 16) ^ sw;
        const bf16x8 kf = *(const bf16x8*)((const char*)Ks + byt);
        acc = __builtin_amdgcn_mfma_f32_16x16x32_bf16(qf[dt], kf, acc, 0, 0, 0);
      }
      sc[ct] = acc;
    }
    __builtin_amdgcn_s_setprio(0);

    // soft-cap + mask + exp(s-50) -> P (bf16) in wave-private LDS
#pragma unroll
    for (int ct = 0; ct < 2; ++ct) {
#pragma unroll
      for (int r = 0; r < 4; ++r) {
        float x = sc[ct][r] * 1.25e-3f;
        x = fminf(fmaxf(x, -8.f), 8.f);
        const float e2 = __expf(2.f * x);
        const float capv = 50.f * (e2 - 1.f) / (e2 + 1.f);
        const float pv = __expf(capv + mv[ct * 4 + r] - 50.f);
        lsum[r] += pv;
        Pb[w][lg * 4 + r][ct * 16 + lc] = (short)f2bf(pv);
      }
    }
    const bf16x8 pfr = *(const bf16x8*)(&Pb[w][lc][lg * 8]);

    // PV from swizzled V LDS
    __builtin_amdgcn_s_setprio(1);
#pragma unroll
    for (int nt = 0; nt < 16; ++nt) {
      const int row = nt * 16 + lc;
      const int byt = (row * 64 + lg * 16) ^ (((row >> 1) & 3) << 4);
      const bf16x8 vf = *(const bf16x8*)((const char*)Vs + byt);
      accO[nt] = __builtin_amdgcn_mfma_f32_16x16x32_bf16(pfr, vf, accO[nt], 0, 0, 0);
    }
    __builtin_amdgcn_s_setprio(0);

    __builtin_amdgcn_s_barrier();   // buf[cur] fully consumed before restage
    cur ^= 1;
  }

#pragma unroll
  for (int mm = 1; mm < 16; mm <<= 1) {
#pragma unroll
    for (int r = 0; r < 4; ++r) lsum[r] += __shfl_xor(lsum[r], mm);
  }
  float rinv[4];
#pragma unroll
  for (int r = 0; r < 4; ++r) rinv[r] = 1.f / lsum[r];

  unsigned short* obase = O + ((size_t)b * Sn + qr0 + lg * 4) * HDn + h * DHn + lc;
#pragma unroll
  for (int nt = 0; nt < 16; ++nt)
#pragma unroll
    for (int r = 0; r < 4; ++r)
      obase[(size_t)r * HDn + nt * 16] = f2bf(accO[nt][r] * rinv[r]);
}

// ---------------------------------------------------------------------------
extern "C" void kernel_launch(void* const* d_in, const int* in_sizes, int n_in,
                              void* d_out, int out_size, void* d_ws, size_t ws_size,
                              hipStream_t stream) {
  (void)in_sizes; (void)n_in; (void)out_size; (void)ws_size;
  const float* hs0  = (const float*)d_in[0];
  const float* hs1  = (const float*)d_in[1];
  const float* hs2  = (const float*)d_in[2];
  const float* mask = (const float*)d_in[3];
  const int*   pos0 = (const int*)d_in[4];
  const int*   pos1 = (const int*)d_in[5];
  const int*   pos2 = (const int*)d_in[6];
  const float* wq[3] = {(const float*)d_in[7],  (const float*)d_in[11], (const float*)d_in[15]};
  const float* wk[3] = {(const float*)d_in[8],  (const float*)d_in[12], (const float*)d_in[16]};
  const float* wv[3] = {(const float*)d_in[9],  (const float*)d_in[13], (const float*)d_in[17]};
  const float* wo[3] = {(const float*)d_in[10], (const float*)d_in[14], (const float*)d_in[18]};
  float* out = (float*)d_out;

  unsigned short* Qh = (unsigned short*)d_ws;                 // [b][h][s][256]
  unsigned short* Kh = Qh + (size_t)Bn * Sn * HDn;            // [b][s][256]
  unsigned short* Vt = Kh + (size_t)Bn * Sn * DHn;            // [b][256][s]
  unsigned short* Ob = Vt + (size_t)Bn * Sn * DHn;            // [b][s][2048]

  const int  Ls[3]   = {968, 6, 50};
  const int  offs[3] = {0, 968, 974};
  const int  hid[3]  = {2048, 1024, 1024};
  const float* hs[3] = {hs0, hs1, hs2};

  for (int g = 0; g < 3; ++g) {
    const int L = Ls[g], Kd = hid[g], off = offs[g], M = Bn * L;
    const int gy = (M + 127) / 128;
    hipLaunchKernelGGL(gemm_qkv, dim3(20, gy), dim3(256), 0, stream,
                       hs[g], wq[g], wk[g], wv[g], Qh, Kh, Vt, L, Kd, off, M);
  }

  hipLaunchKernelGGL(rope_k, dim3(Bn * Sn), dim3(128), 0, stream, Kh, pos0, pos1, pos2);
  hipLaunchKernelGGL(attn_mfma, dim3(Sn / 128, Hn, Bn), dim3(512), 0, stream,
                     Qh, Kh, Vt, mask, pos0, pos1, pos2, Ob);

  size_t ooff = 0;
  for (int g = 0; g < 3; ++g) {
    const int L = Ls[g], N = hid[g], off = offs[g], M = Bn * L;
    const int gy = (M + 127) / 128;
    hipLaunchKernelGGL(gemm_wo, dim3(N / 128, gy), dim3(256), 0, stream,
                       Ob, wo[g], out + ooff, L, HDn, N, Sn, off, M);
    ooff += (size_t)M * N;
  }
}

// Round 7
// 761.901 us; speedup vs baseline: 18.3625x; 1.0530x over previous
//
#include <hip/hip_runtime.h>
#include <hip/hip_bf16.h>
#include <math.h>

namespace {
constexpr int Bn = 8, Sn = 1024, Hn = 8, DHn = 256, HDn = 2048;
}

using bf16x8 = __attribute__((ext_vector_type(8))) short;
using f32x4  = __attribute__((ext_vector_type(4))) float;

__device__ __forceinline__ float bf2f(unsigned short u) {
  unsigned int x = ((unsigned int)u) << 16;
  return __builtin_bit_cast(float, x);
}
__device__ __forceinline__ unsigned short f2bf(float f) {
  unsigned int x = __builtin_bit_cast(unsigned int, f);
  x += 0x7fff + ((x >> 16) & 1);   // RNE
  return (unsigned short)(x >> 16);
}
__device__ __forceinline__ bf16x8 pack8(const float4& u, const float4& v) {
  bf16x8 r;
  r[0] = (short)f2bf(u.x); r[1] = (short)f2bf(u.y); r[2] = (short)f2bf(u.z); r[3] = (short)f2bf(u.w);
  r[4] = (short)f2bf(v.x); r[5] = (short)f2bf(v.y); r[6] = (short)f2bf(v.z); r[7] = (short)f2bf(v.w);
  return r;
}
__device__ __forceinline__ void gload_lds16(const void* g, void* l) {
  __builtin_amdgcn_global_load_lds(
      (const __attribute__((address_space(1))) void*)g,
      (__attribute__((address_space(3))) void*)l, 16, 0, 0);
}

// ---------------------------------------------------------------------------
// convW: W [K][N] fp32 -> tiled swizzled bf16 W^T.
// Chunk (nb, kb) = 128 n-rows x 64 k: 8192 shorts at (nb*(K/64)+kb)*8192.
// Within chunk: row r holds content-granule g (k in [g*8,g*8+8)) at
// granule-position g ^ (r&7)  -> byte = r*128 + (g^(r&7))*16.
// This IS the LDS layout: gemm stages chunks with identity gload_lds.
// ---------------------------------------------------------------------------
__global__ __launch_bounds__(256) void convW(
    const float* __restrict__ W, unsigned short* __restrict__ T, int K, int N)
{
  __shared__ float S[64][132];
  const int nb = blockIdx.x, kb = blockIdx.y;
  const int t = threadIdx.x;
  const int kl = t >> 5, nq = (t & 31) * 4;
  for (int kk = kl; kk < 64; kk += 8) {
    const float4 v = *(const float4*)(W + (size_t)(kb * 64 + kk) * N + nb * 128 + nq);
    S[kk][nq] = v.x; S[kk][nq + 1] = v.y; S[kk][nq + 2] = v.z; S[kk][nq + 3] = v.w;
  }
  __syncthreads();
  unsigned short* chunk = T + ((size_t)nb * (K >> 6) + kb) * 8192;
#pragma unroll
  for (int j = 0; j < 4; ++j) {
    const int q = t * 4 + j;        // granule id 0..1023
    const int r = q >> 3, g = q & 7;
    bf16x8 o;
#pragma unroll
    for (int e = 0; e < 8; ++e) o[e] = (short)f2bf(S[g * 8 + e][r]);
    *(bf16x8*)(chunk + r * 64 + ((g ^ (r & 7)) * 8)) = o;
  }
}

// ---------------------------------------------------------------------------
// QKV GEMM v2: A fp32 (reg-staged, converted, swizzled ds_write), B from
// tiled W^T via gload_lds. Tile 128x128, BK=64, dbuf, counted vmcnt.
// bx<16: Q (head-major), 16-17: K, 18-19: V (transposed).
// ---------------------------------------------------------------------------
__global__ __launch_bounds__(256) void gemm_qkv(
    const float* __restrict__ A, const unsigned short* __restrict__ WT,
    unsigned short* __restrict__ Qh, unsigned short* __restrict__ Kh,
    unsigned short* __restrict__ Vt,
    int L, int K, int c_off, int M_total)
{
  __shared__ __align__(16) short As[2][8192];   // [128 m][64 k] swizzled
  __shared__ __align__(16) short Bs[2][8192];   // [128 n][64 k] swizzled
  const int tid = threadIdx.x;
  const int w  = tid >> 6, l = tid & 63;
  const int wm = w >> 1,  wn = w & 1;
  const int lc = l & 15,  lg = l >> 4;
  const int bx  = blockIdx.x;
  const int bm0 = blockIdx.y * 128;
  const int kbN = K >> 6;

  int region, nbL, cb0;
  if (bx < 16)      { region = 0; nbL = bx;      cb0 = bx * 128; }
  else if (bx < 18) { region = 1; nbL = bx - 16; cb0 = (bx - 16) * 128; }
  else              { region = 2; nbL = bx - 18; cb0 = (bx - 18) * 128; }
  const unsigned short* WTr = WT +
      (region == 0 ? (size_t)0 : (region == 1 ? (size_t)16 * kbN * 8192
                                              : (size_t)18 * kbN * 8192));
  const unsigned short* chunk0 = WTr + (size_t)nbL * kbN * 8192;

  // A staging: thread -> row am = tid>>1, k-half akq = tid&1 (granules akq*4..+3)
  const int am = tid >> 1, akq = tid & 1;
  int mA = bm0 + am;
  if (mA >= M_total) mA = 0;
  const int ab = mA / L, asg = mA - ab * L;
  const float* aP = A + (size_t)(ab * L + asg) * K + akq * 32;

  f32x4 acc[4][4];
#pragma unroll
  for (int i = 0; i < 4; ++i)
#pragma unroll
    for (int j = 0; j < 4; ++j) acc[i][j] = (f32x4){0.f, 0.f, 0.f, 0.f};

  float4 aR[8];
  auto loadA = [&](int kb) {
#pragma unroll
    for (int i = 0; i < 8; ++i) aR[i] = *(const float4*)(aP + (size_t)kb * 64 + i * 4);
  };
  auto writeA = [&](int nb) {
    char* base = (char*)&As[nb][0] + am * 128;
#pragma unroll
    for (int j = 0; j < 4; ++j) {
      const int g = akq * 4 + j;
      *(bf16x8*)(base + ((g ^ (am & 7)) * 16)) = pack8(aR[j * 2], aR[j * 2 + 1]);
    }
  };
  auto issueB = [&](int kb, int nb) {
    const char* src = (const char*)(chunk0 + (size_t)kb * 8192);
    char* dst = (char*)&Bs[nb][0];
#pragma unroll
    for (int j = 0; j < 4; ++j)
      gload_lds16(src + tid * 16 + j * 4096, dst + tid * 16 + j * 4096);
  };

  loadA(0); issueB(0, 0);
  for (int kt = 0; kt < kbN; ++kt) {
    const int cur = kt & 1;
    writeA(cur);
    asm volatile("s_waitcnt lgkmcnt(0)" ::: "memory");
    __builtin_amdgcn_s_barrier();          // prev compute done; A(kt) visible
    if (kt + 1 < kbN) {
      loadA(kt + 1); issueB(kt + 1, cur ^ 1);
      asm volatile("s_waitcnt vmcnt(12)" ::: "memory");   // B(kt) arrived
    } else {
      asm volatile("s_waitcnt vmcnt(0)" ::: "memory");
    }
    __builtin_amdgcn_s_barrier();
    __builtin_amdgcn_sched_barrier(0);
#pragma unroll
    for (int kk = 0; kk < 2; ++kk) {
      bf16x8 af[4], bfg[4];
#pragma unroll
      for (int mi = 0; mi < 4; ++mi) {
        const int row = wm * 64 + mi * 16 + lc;
        af[mi] = *(const bf16x8*)((const char*)&As[cur][0] + row * 128 +
                                  (((kk * 4 + lg) ^ (row & 7)) * 16));
      }
#pragma unroll
      for (int ni = 0; ni < 4; ++ni) {
        const int row = wn * 64 + ni * 16 + lc;
        bfg[ni] = *(const bf16x8*)((const char*)&Bs[cur][0] + row * 128 +
                                   (((kk * 4 + lg) ^ (row & 7)) * 16));
      }
#pragma unroll
      for (int mi = 0; mi < 4; ++mi)
#pragma unroll
        for (int ni = 0; ni < 4; ++ni)
          acc[mi][ni] = __builtin_amdgcn_mfma_f32_16x16x32_bf16(af[mi], bfg[ni], acc[mi][ni], 0, 0, 0);
    }
  }

#pragma unroll
  for (int mi = 0; mi < 4; ++mi) {
    const int gm = bm0 + wm * 64 + mi * 16 + lg * 4;
#pragma unroll
    for (int r = 0; r < 4; ++r) {
      const int m = gm + r;
      if (m < M_total) {
        const int cb = m / L, cs = m - cb * L;
#pragma unroll
        for (int ni = 0; ni < 4; ++ni) {
          const int colL = cb0 + wn * 64 + ni * 16 + lc;
          const unsigned short v = f2bf(acc[mi][ni][r]);
          if (region == 0) {
            const int hh = colL >> 8, dd = colL & 255;
            Qh[(((size_t)cb * Hn + hh) * Sn + c_off + cs) * DHn + dd] = v;
          } else if (region == 1) {
            Kh[((size_t)cb * Sn + c_off + cs) * DHn + colL] = v;
          } else {
            Vt[((size_t)cb * DHn + colL) * Sn + c_off + cs] = v;
          }
        }
      }
    }
  }
}

// ---------------------------------------------------------------------------
// Output-projection GEMM v2: A (Ob bf16) AND B (tiled wo^T) via gload_lds.
// Tile 128x128, BK=64, dbuf, counted vmcnt(8).
// ---------------------------------------------------------------------------
__global__ __launch_bounds__(256) void gemm_wo(
    const unsigned short* __restrict__ A, const unsigned short* __restrict__ WT,
    float* __restrict__ C, int L, int N, int a_off, int M_total)
{
  __shared__ __align__(16) short As[2][8192];
  __shared__ __align__(16) short Bs[2][8192];
  const int tid = threadIdx.x;
  const int w  = tid >> 6, l = tid & 63;
  const int wm = w >> 1,  wn = w & 1;
  const int lc = l & 15,  lg = l >> 4;
  const int bn0 = blockIdx.x * 128;
  const int bm0 = blockIdx.y * 128;
  const int kbN = 32;  // K = 2048

  const unsigned short* chunk0 = WT + (size_t)blockIdx.x * kbN * 8192;

  // A source rows for this thread's 4 granules (fixed across tiles)
  const char* aRow[4];
  const int gpos = tid & 7;
#pragma unroll
  for (int j = 0; j < 4; ++j) {
    const int ml = (tid >> 3) + j * 32;
    int m = bm0 + ml;
    if (m >= M_total) m = 0;
    const int cb = m / L, cs = m - cb * L;
    const int gc = gpos ^ (ml & 7);     // content granule for this slot
    aRow[j] = (const char*)(A + (size_t)(cb * Sn + a_off + cs) * HDn) + gc * 16;
  }

  f32x4 acc[4][4];
#pragma unroll
  for (int i = 0; i < 4; ++i)
#pragma unroll
    for (int j = 0; j < 4; ++j) acc[i][j] = (f32x4){0.f, 0.f, 0.f, 0.f};

  auto issueA = [&](int kb, int nb) {
    char* dst = (char*)&As[nb][0];
#pragma unroll
    for (int j = 0; j < 4; ++j)
      gload_lds16(aRow[j] + (size_t)kb * 128, dst + tid * 16 + j * 4096);
  };
  auto issueB = [&](int kb, int nb) {
    const char* src = (const char*)(chunk0 + (size_t)kb * 8192);
    char* dst = (char*)&Bs[nb][0];
#pragma unroll
    for (int j = 0; j < 4; ++j)
      gload_lds16(src + tid * 16 + j * 4096, dst + tid * 16 + j * 4096);
  };

  issueA(0, 0); issueB(0, 0);
  for (int kt = 0; kt < kbN; ++kt) {
    const int cur = kt & 1;
    __builtin_amdgcn_s_barrier();          // prev compute done
    if (kt + 1 < kbN) {
      issueA(kt + 1, cur ^ 1); issueB(kt + 1, cur ^ 1);
      asm volatile("s_waitcnt vmcnt(8)" ::: "memory");   // tile kt arrived
    } else {
      asm volatile("s_waitcnt vmcnt(0)" ::: "memory");
    }
    __builtin_amdgcn_s_barrier();
    __builtin_amdgcn_sched_barrier(0);
#pragma unroll
    for (int kk = 0; kk < 2; ++kk) {
      bf16x8 af[4], bfg[4];
#pragma unroll
      for (int mi = 0; mi < 4; ++mi) {
        const int row = wm * 64 + mi * 16 + lc;
        af[mi] = *(const bf16x8*)((const char*)&As[cur][0] + row * 128 +
                                  (((kk * 4 + lg) ^ (row & 7)) * 16));
      }
#pragma unroll
      for (int ni = 0; ni < 4; ++ni) {
        const int row = wn * 64 + ni * 16 + lc;
        bfg[ni] = *(const bf16x8*)((const char*)&Bs[cur][0] + row * 128 +
                                   (((kk * 4 + lg) ^ (row & 7)) * 16));
      }
#pragma unroll
      for (int mi = 0; mi < 4; ++mi)
#pragma unroll
        for (int ni = 0; ni < 4; ++ni)
          acc[mi][ni] = __builtin_amdgcn_mfma_f32_16x16x32_bf16(af[mi], bfg[ni], acc[mi][ni], 0, 0, 0);
    }
  }

#pragma unroll
  for (int mi = 0; mi < 4; ++mi) {
    const int gm = bm0 + wm * 64 + mi * 16 + lg * 4;
#pragma unroll
    for (int r = 0; r < 4; ++r) {
      const int m = gm + r;
      if (m < M_total) {
        const int cb = m / L, cs = m - cb * L;
#pragma unroll
        for (int ni = 0; ni < 4; ++ni) {
          const int col = bn0 + wn * 64 + ni * 16 + lc;
          C[(size_t)(cb * L + cs) * N + col] = acc[mi][ni][r];
        }
      }
    }
  }
}

// ---------------------------------------------------------------------------
// RoPE in place on bf16 K [b][s][256] (Q rope fused into attention).
// ---------------------------------------------------------------------------
__global__ __launch_bounds__(128) void rope_k(
    unsigned short* __restrict__ Kh,
    const int* __restrict__ p0, const int* __restrict__ p1, const int* __restrict__ p2)
{
  const int t = blockIdx.x, b = t >> 10, s = t & 1023;
  int p;
  if (s < 968)      p = p0[b * 968 + s];
  else if (s < 974) p = p1[b * 6 + (s - 968)];
  else              p = p2[b * 50 + (s - 974)];
  const float pf = (float)p;
  const float c0 = -0.07195578415606394f;  // -ln(10000)/128
  const int d = threadIdx.x;
  const float inv = __expf(c0 * (float)d);
  float cs, sn;
  sincosf(pf * inv, &sn, &cs);
  unsigned short* base = Kh + ((size_t)b * Sn + s) * DHn;
  const float x1 = bf2f(base[d]), x2 = bf2f(base[d + 128]);
  base[d]       = f2bf(x1 * cs - x2 * sn);
  base[d + 128] = f2bf(x2 * cs + x1 * sn);
}

// ---------------------------------------------------------------------------
// MFMA flash attention (round-6 structure, unchanged).
// ---------------------------------------------------------------------------
__global__ __launch_bounds__(512) void attn_mfma(
    const unsigned short* __restrict__ Qh, const unsigned short* __restrict__ Kh,
    const unsigned short* __restrict__ Vt, const float* __restrict__ mask,
    const int* __restrict__ p0, const int* __restrict__ p1, const int* __restrict__ p2,
    unsigned short* __restrict__ O)
{
  __shared__ __align__(16) short KsB[2][8192];
  __shared__ __align__(16) short VsB[2][8192];
  __shared__ short Pb[8][16][32];
  const int tid = threadIdx.x;
  const int w  = tid >> 6;
  const int l  = tid & 63;
  const int lc = l & 15;
  const int lg = l >> 4;
  const int q0 = blockIdx.x * 128;
  const int h  = blockIdx.y;
  const int b  = blockIdx.z;
  const int qr0 = q0 + w * 16;
  const int srow = qr0 + lc;

  int p;
  if (srow < 968)      p = p0[b * 968 + srow];
  else if (srow < 974) p = p1[b * 6 + (srow - 968)];
  else                 p = p2[b * 50 + (srow - 974)];
  const float pf = (float)p;
  const float c0 = -0.07195578415606394f;

  const unsigned short* qrow = Qh + (((size_t)b * Hn + h) * Sn + srow) * DHn;
  bf16x8 qf[8];
#pragma unroll
  for (int dt = 0; dt < 8; ++dt)
    qf[dt] = *(const bf16x8*)(qrow + dt * 32 + lg * 8);
#pragma unroll
  for (int dt = 0; dt < 4; ++dt) {
#pragma unroll
    for (int j = 0; j < 8; ++j) {
      const int d = dt * 32 + lg * 8 + j;
      const float inv = __expf(c0 * (float)d);
      float cs, sn;
      sincosf(pf * inv, &sn, &cs);
      const float x1 = bf2f((unsigned short)qf[dt][j]);
      const float x2 = bf2f((unsigned short)qf[dt + 4][j]);
      qf[dt][j]     = (short)f2bf(x1 * cs - x2 * sn);
      qf[dt + 4][j] = (short)f2bf(x2 * cs + x1 * sn);
    }
  }

  f32x4 accO[16];
#pragma unroll
  for (int i = 0; i < 16; ++i) accO[i] = (f32x4){0.f, 0.f, 0.f, 0.f};
  float lsum[4] = {0.f, 0.f, 0.f, 0.f};

  const char* KgB = (const char*)(Kh + (size_t)b * Sn * DHn);
  const char* VgB = (const char*)(Vt + (size_t)b * DHn * Sn);
  const float* mbase = mask + (size_t)b * Sn * Sn + (size_t)(qr0 + lg * 4) * Sn;

  auto stage = [&](int kt, int nb) {
    const char* kg = KgB + (size_t)kt * 16384;
    const char* vg = VgB + (size_t)kt * 64;
#pragma unroll
    for (int j = 0; j < 2; ++j) {
      const int chunk = w * 2 + j;
      const int o = chunk * 1024 + l * 16;
      const int srcK = o ^ (((o >> 9) & 7) << 4);
      gload_lds16(kg + srcK, (char*)&KsB[nb][0] + chunk * 1024);
    }
#pragma unroll
    for (int j = 0; j < 2; ++j) {
      const int chunk = w * 2 + j;
      const int o = chunk * 1024 + l * 16;
      const int x = o ^ (((o >> 7) & 3) << 4);
      gload_lds16(vg + (size_t)(x >> 6) * 2048 + (x & 63),
                  (char*)&VsB[nb][0] + chunk * 1024);
    }
  };

  stage(0, 0);
  int cur = 0;
  for (int kt = 0; kt < 32; ++kt) {
    const int k0 = kt * 32;
    if (kt + 1 < 32) {
      stage(kt + 1, cur ^ 1);
      asm volatile("s_waitcnt vmcnt(4)" ::: "memory");
    } else {
      asm volatile("s_waitcnt vmcnt(0)" ::: "memory");
    }
    __builtin_amdgcn_s_barrier();
    __builtin_amdgcn_sched_barrier(0);

    const short* Ks = &KsB[cur][0];
    const short* Vs = &VsB[cur][0];

    float mv[8];
#pragma unroll
    for (int ct = 0; ct < 2; ++ct)
#pragma unroll
      for (int r = 0; r < 4; ++r)
        mv[ct * 4 + r] = mbase[(size_t)r * Sn + k0 + ct * 16 + lc];

    f32x4 sc[2];
    __builtin_amdgcn_s_setprio(1);
#pragma unroll
    for (int ct = 0; ct < 2; ++ct) {
      f32x4 acc = (f32x4){0.f, 0.f, 0.f, 0.f};
      const int row = ct * 16 + lc;
      const int sw = (row & 7) << 4;
#pragma unroll
      for (int dt = 0; dt < 8; ++dt) {
        const int byt = (row * 512 + dt * 64 + lg * 16) ^ sw;
        const bf16x8 kf = *(const bf16x8*)((const char*)Ks + byt);
        acc = __builtin_amdgcn_mfma_f32_16x16x32_bf16(qf[dt], kf, acc, 0, 0, 0);
      }
      sc[ct] = acc;
    }
    __builtin_amdgcn_s_setprio(0);

#pragma unroll
    for (int ct = 0; ct < 2; ++ct) {
#pragma unroll
      for (int r = 0; r < 4; ++r) {
        float x = sc[ct][r] * 1.25e-3f;
        x = fminf(fmaxf(x, -8.f), 8.f);
        const float e2 = __expf(2.f * x);
        const float capv = 50.f * (e2 - 1.f) / (e2 + 1.f);
        const float pv = __expf(capv + mv[ct * 4 + r] - 50.f);
        lsum[r] += pv;
        Pb[w][lg * 4 + r][ct * 16 + lc] = (short)f2bf(pv);
      }
    }
    const bf16x8 pfr = *(const bf16x8*)(&Pb[w][lc][lg * 8]);

    __builtin_amdgcn_s_setprio(1);
#pragma unroll
    for (int nt = 0; nt < 16; ++nt) {
      const int row = nt * 16 + lc;
      const int byt = (row * 64 + lg * 16) ^ (((row >> 1) & 3) << 4);
      const bf16x8 vf = *(const bf16x8*)((const char*)Vs + byt);
      accO[nt] = __builtin_amdgcn_mfma_f32_16x16x32_bf16(pfr, vf, accO[nt], 0, 0, 0);
    }
    __builtin_amdgcn_s_setprio(0);

    __builtin_amdgcn_s_barrier();
    cur ^= 1;
  }

#pragma unroll
  for (int mm = 1; mm < 16; mm <<= 1) {
#pragma unroll
    for (int r = 0; r < 4; ++r) lsum[r] += __shfl_xor(lsum[r], mm);
  }
  float rinv[4];
#pragma unroll
  for (int r = 0; r < 4; ++r) rinv[r] = 1.f / lsum[r];

  unsigned short* obase = O + ((size_t)b * Sn + qr0 + lg * 4) * HDn + h * DHn + lc;
#pragma unroll
  for (int nt = 0; nt < 16; ++nt)
#pragma unroll
    for (int r = 0; r < 4; ++r)
      obase[(size_t)r * HDn + nt * 16] = f2bf(accO[nt][r] * rinv[r]);
}

// ---------------------------------------------------------------------------
extern "C" void kernel_launch(void* const* d_in, const int* in_sizes, int n_in,
                              void* d_out, int out_size, void* d_ws, size_t ws_size,
                              hipStream_t stream) {
  (void)in_sizes; (void)n_in; (void)out_size; (void)ws_size;
  const float* hs0  = (const float*)d_in[0];
  const float* hs1  = (const float*)d_in[1];
  const float* hs2  = (const float*)d_in[2];
  const float* mask = (const float*)d_in[3];
  const int*   pos0 = (const int*)d_in[4];
  const int*   pos1 = (const int*)d_in[5];
  const int*   pos2 = (const int*)d_in[6];
  const float* wq[3] = {(const float*)d_in[7],  (const float*)d_in[11], (const float*)d_in[15]};
  const float* wk[3] = {(const float*)d_in[8],  (const float*)d_in[12], (const float*)d_in[16]};
  const float* wv[3] = {(const float*)d_in[9],  (const float*)d_in[13], (const float*)d_in[17]};
  const float* wo[3] = {(const float*)d_in[10], (const float*)d_in[14], (const float*)d_in[18]};
  float* out = (float*)d_out;

  // ws: Qh [b][h][s][256] (33.5 MB; later reused for woT 16.8 MB)
  //     Kh [b][s][256] | Vt [b][256][s]
  //     Ob [b][s][2048] (33.5 MB; first 21 MB hold qkvT until attn writes)
  unsigned short* Qh = (unsigned short*)d_ws;
  unsigned short* Kh = Qh + (size_t)Bn * Sn * HDn;
  unsigned short* Vt = Kh + (size_t)Bn * Sn * DHn;
  unsigned short* Ob = Vt + (size_t)Bn * Sn * DHn;
  unsigned short* qkvT = Ob;      // dead until attn
  unsigned short* woT  = Qh;      // dead after attn

  const int  Ls[3]   = {968, 6, 50};
  const int  offs[3] = {0, 968, 974};
  const int  Ks_[3]  = {2048, 1024, 1024};
  const float* hs[3] = {hs0, hs1, hs2};

  // qkvT segment bases (in shorts): 20 n-blocks x (K/64) chunks x 8192
  size_t qb[3]; qb[0] = 0;
  qb[1] = qb[0] + (size_t)20 * (Ks_[0] >> 6) * 8192;
  qb[2] = qb[1] + (size_t)20 * (Ks_[1] >> 6) * 8192;
  // woT segment bases: (hid/128) n-blocks x 32 chunks x 8192
  size_t ob[3]; ob[0] = 0;
  ob[1] = ob[0] + (size_t)16 * 32 * 8192;
  ob[2] = ob[1] + (size_t)8 * 32 * 8192;

  // --- convert QKV weights into qkvT (Ob region) ---
  for (int g = 0; g < 3; ++g) {
    const int K = Ks_[g], kbN = K >> 6;
    hipLaunchKernelGGL(convW, dim3(16, kbN), dim3(256), 0, stream,
                       wq[g], qkvT + qb[g], K, HDn);
    hipLaunchKernelGGL(convW, dim3(2, kbN), dim3(256), 0, stream,
                       wk[g], qkvT + qb[g] + (size_t)16 * kbN * 8192, K, DHn);
    hipLaunchKernelGGL(convW, dim3(2, kbN), dim3(256), 0, stream,
                       wv[g], qkvT + qb[g] + (size_t)18 * kbN * 8192, K, DHn);
  }

  // --- QKV projections ---
  for (int g = 0; g < 3; ++g) {
    const int L = Ls[g], K = Ks_[g], off = offs[g], M = Bn * L;
    const int gy = (M + 127) / 128;
    hipLaunchKernelGGL(gemm_qkv, dim3(20, gy), dim3(256), 0, stream,
                       hs[g], qkvT + qb[g], Qh, Kh, Vt, L, K, off, M);
  }

  hipLaunchKernelGGL(rope_k, dim3(Bn * Sn), dim3(128), 0, stream, Kh, pos0, pos1, pos2);
  hipLaunchKernelGGL(attn_mfma, dim3(Sn / 128, Hn, Bn), dim3(512), 0, stream,
                     Qh, Kh, Vt, mask, pos0, pos1, pos2, Ob);

  // --- convert WO weights into woT (Qh region, dead after attn) ---
  for (int g = 0; g < 3; ++g) {
    const int N = (g == 0) ? 2048 : 1024;
    hipLaunchKernelGGL(convW, dim3(N / 128, 32), dim3(256), 0, stream,
                       wo[g], woT + ob[g], HDn, N);
  }

  // --- output projections ---
  size_t ooff = 0;
  for (int g = 0; g < 3; ++g) {
    const int L = Ls[g], N = (g == 0) ? 2048 : 1024, off = offs[g], M = Bn * L;
    const int gy = (M + 127) / 128;
    hipLaunchKernelGGL(gemm_wo, dim3(N / 128, gy), dim3(256), 0, stream,
                       Ob, woT + ob[g], out + ooff, L, N, off, M);
    ooff += (size_t)M * N;
  }
}

// Round 8
// 599.612 us; speedup vs baseline: 23.3324x; 1.2707x over previous
//
#include <hip/hip_runtime.h>
#include <hip/hip_bf16.h>
#include <math.h>

namespace {
constexpr int Bn = 8, Sn = 1024, Hn = 8, DHn = 256, HDn = 2048;
}

using bf16x8 = __attribute__((ext_vector_type(8))) short;
using f32x4  = __attribute__((ext_vector_type(4))) float;

__device__ __forceinline__ float bf2f(unsigned short u) {
  unsigned int x = ((unsigned int)u) << 16;
  return __builtin_bit_cast(float, x);
}
__device__ __forceinline__ unsigned short f2bf(float f) {
  unsigned int x = __builtin_bit_cast(unsigned int, f);
  x += 0x7fff + ((x >> 16) & 1);   // RNE
  return (unsigned short)(x >> 16);
}
__device__ __forceinline__ bf16x8 pack8(const float4& u, const float4& v) {
  bf16x8 r;
  r[0] = (short)f2bf(u.x); r[1] = (short)f2bf(u.y); r[2] = (short)f2bf(u.z); r[3] = (short)f2bf(u.w);
  r[4] = (short)f2bf(v.x); r[5] = (short)f2bf(v.y); r[6] = (short)f2bf(v.z); r[7] = (short)f2bf(v.w);
  return r;
}
__device__ __forceinline__ void gload_lds16(const void* g, void* l) {
  __builtin_amdgcn_global_load_lds(
      (const __attribute__((address_space(1))) void*)g,
      (__attribute__((address_space(3))) void*)l, 16, 0, 0);
}

// ---------------------------------------------------------------------------
// Chunk layout (shared by convW / conv_hs / both GEMMs):
// chunk = 128 rows x 64 k of bf16 = 8192 shorts = 16 KB.
// row r, granule g (k in [g*8,g*8+8)) at byte r*128 + ((g^(r&7))*16).
// Stored byte-for-byte as the LDS image -> staging is identity gload_lds.
// ---------------------------------------------------------------------------

// convW: W [K][N] fp32 -> chunks over (nb, kb); rows of chunk = n.
__global__ __launch_bounds__(256) void convW(
    const float* __restrict__ W, unsigned short* __restrict__ T, int K, int N)
{
  __shared__ float S[64][132];
  const int nb = blockIdx.x, kb = blockIdx.y;
  const int t = threadIdx.x;
  const int kl = t >> 5, nq = (t & 31) * 4;
  for (int kk = kl; kk < 64; kk += 8) {
    const float4 v = *(const float4*)(W + (size_t)(kb * 64 + kk) * N + nb * 128 + nq);
    S[kk][nq] = v.x; S[kk][nq + 1] = v.y; S[kk][nq + 2] = v.z; S[kk][nq + 3] = v.w;
  }
  __syncthreads();
  unsigned short* chunk = T + ((size_t)nb * (K >> 6) + kb) * 8192;
#pragma unroll
  for (int j = 0; j < 4; ++j) {
    const int q = t * 4 + j;
    const int r = q >> 3, g = q & 7;
    bf16x8 o;
#pragma unroll
    for (int e = 0; e < 8; ++e) o[e] = (short)f2bf(S[g * 8 + e][r]);
    *(bf16x8*)(chunk + r * 64 + ((g ^ (r & 7)) * 8)) = o;
  }
}

// conv_hs: activations [M][K] fp32 (rows are k-contiguous) -> chunks (mb, kb).
__global__ __launch_bounds__(256) void conv_hs(
    const float* __restrict__ A, unsigned short* __restrict__ T, int K, int M_total)
{
  const int mb = blockIdx.x, kb = blockIdx.y;
  const int kbN = K >> 6;
  unsigned short* chunk = T + ((size_t)mb * kbN + kb) * 8192;
#pragma unroll
  for (int j = 0; j < 4; ++j) {
    const int q = j * 256 + threadIdx.x;   // granule id 0..1023
    const int r = q >> 3, g = q & 7;
    int m = mb * 128 + r;
    if (m >= M_total) m = mb * 128;        // clamp (finite filler)
    const float* src = A + (size_t)m * K + kb * 64 + g * 8;
    const float4 u = *(const float4*)(src);
    const float4 v = *(const float4*)(src + 4);
    *(bf16x8*)(chunk + r * 64 + ((g ^ (r & 7)) * 8)) = pack8(u, v);
  }
}

// ---------------------------------------------------------------------------
// QKV GEMM v3: BOTH operands from pre-tiled chunks via identity gload_lds.
// Tile 128x128, BK=64, dbuf, counted vmcnt(8).
// bx<16: Q (head-major out), 16-17: K, 18-19: V (transposed).
// ---------------------------------------------------------------------------
__global__ __launch_bounds__(256) void gemm_qkv(
    const unsigned short* __restrict__ AT, const unsigned short* __restrict__ WT,
    unsigned short* __restrict__ Qh, unsigned short* __restrict__ Kh,
    unsigned short* __restrict__ Vt,
    int L, int K, int c_off, int M_total)
{
  __shared__ __align__(16) short As[2][8192];
  __shared__ __align__(16) short Bs[2][8192];
  const int tid = threadIdx.x;
  const int w  = tid >> 6, l = tid & 63;
  const int wm = w >> 1,  wn = w & 1;
  const int lc = l & 15,  lg = l >> 4;
  const int bx  = blockIdx.x;
  const int bm0 = blockIdx.y * 128;
  const int kbN = K >> 6;

  int region, nbL, cb0;
  if (bx < 16)      { region = 0; nbL = bx;      cb0 = bx * 128; }
  else if (bx < 18) { region = 1; nbL = bx - 16; cb0 = (bx - 16) * 128; }
  else              { region = 2; nbL = bx - 18; cb0 = (bx - 18) * 128; }
  const unsigned short* WTr = WT +
      (region == 0 ? (size_t)0 : (region == 1 ? (size_t)16 * kbN * 8192
                                              : (size_t)18 * kbN * 8192));
  const unsigned short* bChunk0 = WTr + (size_t)nbL * kbN * 8192;
  const unsigned short* aChunk0 = AT + (size_t)blockIdx.y * kbN * 8192;

  f32x4 acc[4][4];
#pragma unroll
  for (int i = 0; i < 4; ++i)
#pragma unroll
    for (int j = 0; j < 4; ++j) acc[i][j] = (f32x4){0.f, 0.f, 0.f, 0.f};

  auto issueA = [&](int kb, int nb) {
    const char* src = (const char*)(aChunk0 + (size_t)kb * 8192);
    char* dst = (char*)&As[nb][0];
#pragma unroll
    for (int j = 0; j < 4; ++j)
      gload_lds16(src + tid * 16 + j * 4096, dst + tid * 16 + j * 4096);
  };
  auto issueB = [&](int kb, int nb) {
    const char* src = (const char*)(bChunk0 + (size_t)kb * 8192);
    char* dst = (char*)&Bs[nb][0];
#pragma unroll
    for (int j = 0; j < 4; ++j)
      gload_lds16(src + tid * 16 + j * 4096, dst + tid * 16 + j * 4096);
  };

  issueA(0, 0); issueB(0, 0);
  for (int kt = 0; kt < kbN; ++kt) {
    const int cur = kt & 1;
    __builtin_amdgcn_s_barrier();          // prev compute done (buf cur^1 free)
    if (kt + 1 < kbN) {
      issueA(kt + 1, cur ^ 1); issueB(kt + 1, cur ^ 1);
      asm volatile("s_waitcnt vmcnt(8)" ::: "memory");   // tile kt arrived
    } else {
      asm volatile("s_waitcnt vmcnt(0)" ::: "memory");
    }
    __builtin_amdgcn_s_barrier();
    __builtin_amdgcn_sched_barrier(0);
#pragma unroll
    for (int kk = 0; kk < 2; ++kk) {
      bf16x8 af[4], bfg[4];
#pragma unroll
      for (int mi = 0; mi < 4; ++mi) {
        const int row = wm * 64 + mi * 16 + lc;
        af[mi] = *(const bf16x8*)((const char*)&As[cur][0] + row * 128 +
                                  (((kk * 4 + lg) ^ (row & 7)) * 16));
      }
#pragma unroll
      for (int ni = 0; ni < 4; ++ni) {
        const int row = wn * 64 + ni * 16 + lc;
        bfg[ni] = *(const bf16x8*)((const char*)&Bs[cur][0] + row * 128 +
                                   (((kk * 4 + lg) ^ (row & 7)) * 16));
      }
#pragma unroll
      for (int mi = 0; mi < 4; ++mi)
#pragma unroll
        for (int ni = 0; ni < 4; ++ni)
          acc[mi][ni] = __builtin_amdgcn_mfma_f32_16x16x32_bf16(af[mi], bfg[ni], acc[mi][ni], 0, 0, 0);
    }
  }

#pragma unroll
  for (int mi = 0; mi < 4; ++mi) {
    const int gm = bm0 + wm * 64 + mi * 16 + lg * 4;
#pragma unroll
    for (int r = 0; r < 4; ++r) {
      const int m = gm + r;
      if (m < M_total) {
        const int cb = m / L, cs = m - cb * L;
#pragma unroll
        for (int ni = 0; ni < 4; ++ni) {
          const int colL = cb0 + wn * 64 + ni * 16 + lc;
          const unsigned short v = f2bf(acc[mi][ni][r]);
          if (region == 0) {
            const int hh = colL >> 8, dd = colL & 255;
            Qh[(((size_t)cb * Hn + hh) * Sn + c_off + cs) * DHn + dd] = v;
          } else if (region == 1) {
            Kh[((size_t)cb * Sn + c_off + cs) * DHn + colL] = v;
          } else {
            Vt[((size_t)cb * DHn + colL) * Sn + c_off + cs] = v;
          }
        }
      }
    }
  }
}

// ---------------------------------------------------------------------------
// Output-projection GEMM (unchanged from round 7): A (Ob bf16, per-lane
// pre-swizzled source) and B (tiled wo^T) via gload_lds. BK=64, vmcnt(8).
// ---------------------------------------------------------------------------
__global__ __launch_bounds__(256) void gemm_wo(
    const unsigned short* __restrict__ A, const unsigned short* __restrict__ WT,
    float* __restrict__ C, int L, int N, int a_off, int M_total)
{
  __shared__ __align__(16) short As[2][8192];
  __shared__ __align__(16) short Bs[2][8192];
  const int tid = threadIdx.x;
  const int w  = tid >> 6, l = tid & 63;
  const int wm = w >> 1,  wn = w & 1;
  const int lc = l & 15,  lg = l >> 4;
  const int bn0 = blockIdx.x * 128;
  const int bm0 = blockIdx.y * 128;
  const int kbN = 32;  // K = 2048

  const unsigned short* chunk0 = WT + (size_t)blockIdx.x * kbN * 8192;

  const char* aRow[4];
  const int gpos = tid & 7;
#pragma unroll
  for (int j = 0; j < 4; ++j) {
    const int ml = (tid >> 3) + j * 32;
    int m = bm0 + ml;
    if (m >= M_total) m = 0;
    const int cb = m / L, cs = m - cb * L;
    const int gc = gpos ^ (ml & 7);
    aRow[j] = (const char*)(A + (size_t)(cb * Sn + a_off + cs) * HDn) + gc * 16;
  }

  f32x4 acc[4][4];
#pragma unroll
  for (int i = 0; i < 4; ++i)
#pragma unroll
    for (int j = 0; j < 4; ++j) acc[i][j] = (f32x4){0.f, 0.f, 0.f, 0.f};

  auto issueA = [&](int kb, int nb) {
    char* dst = (char*)&As[nb][0];
#pragma unroll
    for (int j = 0; j < 4; ++j)
      gload_lds16(aRow[j] + (size_t)kb * 128, dst + tid * 16 + j * 4096);
  };
  auto issueB = [&](int kb, int nb) {
    const char* src = (const char*)(chunk0 + (size_t)kb * 8192);
    char* dst = (char*)&Bs[nb][0];
#pragma unroll
    for (int j = 0; j < 4; ++j)
      gload_lds16(src + tid * 16 + j * 4096, dst + tid * 16 + j * 4096);
  };

  issueA(0, 0); issueB(0, 0);
  for (int kt = 0; kt < kbN; ++kt) {
    const int cur = kt & 1;
    __builtin_amdgcn_s_barrier();
    if (kt + 1 < kbN) {
      issueA(kt + 1, cur ^ 1); issueB(kt + 1, cur ^ 1);
      asm volatile("s_waitcnt vmcnt(8)" ::: "memory");
    } else {
      asm volatile("s_waitcnt vmcnt(0)" ::: "memory");
    }
    __builtin_amdgcn_s_barrier();
    __builtin_amdgcn_sched_barrier(0);
#pragma unroll
    for (int kk = 0; kk < 2; ++kk) {
      bf16x8 af[4], bfg[4];
#pragma unroll
      for (int mi = 0; mi < 4; ++mi) {
        const int row = wm * 64 + mi * 16 + lc;
        af[mi] = *(const bf16x8*)((const char*)&As[cur][0] + row * 128 +
                                  (((kk * 4 + lg) ^ (row & 7)) * 16));
      }
#pragma unroll
      for (int ni = 0; ni < 4; ++ni) {
        const int row = wn * 64 + ni * 16 + lc;
        bfg[ni] = *(const bf16x8*)((const char*)&Bs[cur][0] + row * 128 +
                                   (((kk * 4 + lg) ^ (row & 7)) * 16));
      }
#pragma unroll
      for (int mi = 0; mi < 4; ++mi)
#pragma unroll
        for (int ni = 0; ni < 4; ++ni)
          acc[mi][ni] = __builtin_amdgcn_mfma_f32_16x16x32_bf16(af[mi], bfg[ni], acc[mi][ni], 0, 0, 0);
    }
  }

#pragma unroll
  for (int mi = 0; mi < 4; ++mi) {
    const int gm = bm0 + wm * 64 + mi * 16 + lg * 4;
#pragma unroll
    for (int r = 0; r < 4; ++r) {
      const int m = gm + r;
      if (m < M_total) {
        const int cb = m / L, cs = m - cb * L;
#pragma unroll
        for (int ni = 0; ni < 4; ++ni) {
          const int col = bn0 + wn * 64 + ni * 16 + lc;
          C[(size_t)(cb * L + cs) * N + col] = acc[mi][ni][r];
        }
      }
    }
  }
}

// ---------------------------------------------------------------------------
// RoPE in place on bf16 K [b][s][256] (Q rope fused into attention).
// ---------------------------------------------------------------------------
__global__ __launch_bounds__(128) void rope_k(
    unsigned short* __restrict__ Kh,
    const int* __restrict__ p0, const int* __restrict__ p1, const int* __restrict__ p2)
{
  const int t = blockIdx.x, b = t >> 10, s = t & 1023;
  int p;
  if (s < 968)      p = p0[b * 968 + s];
  else if (s < 974) p = p1[b * 6 + (s - 968)];
  else              p = p2[b * 50 + (s - 974)];
  const float pf = (float)p;
  const float c0 = -0.07195578415606394f;  // -ln(10000)/128
  const int d = threadIdx.x;
  const float inv = __expf(c0 * (float)d);
  float cs, sn;
  sincosf(pf * inv, &sn, &cs);
  unsigned short* base = Kh + ((size_t)b * Sn + s) * DHn;
  const float x1 = bf2f(base[d]), x2 = bf2f(base[d + 128]);
  base[d]       = f2bf(x1 * cs - x2 * sn);
  base[d + 128] = f2bf(x2 * cs + x1 * sn);
}

// ---------------------------------------------------------------------------
// MFMA flash attention (round-6 structure, unchanged).
// ---------------------------------------------------------------------------
__global__ __launch_bounds__(512) void attn_mfma(
    const unsigned short* __restrict__ Qh, const unsigned short* __restrict__ Kh,
    const unsigned short* __restrict__ Vt, const float* __restrict__ mask,
    const int* __restrict__ p0, const int* __restrict__ p1, const int* __restrict__ p2,
    unsigned short* __restrict__ O)
{
  __shared__ __align__(16) short KsB[2][8192];
  __shared__ __align__(16) short VsB[2][8192];
  __shared__ short Pb[8][16][32];
  const int tid = threadIdx.x;
  const int w  = tid >> 6;
  const int l  = tid & 63;
  const int lc = l & 15;
  const int lg = l >> 4;
  const int q0 = blockIdx.x * 128;
  const int h  = blockIdx.y;
  const int b  = blockIdx.z;
  const int qr0 = q0 + w * 16;
  const int srow = qr0 + lc;

  int p;
  if (srow < 968)      p = p0[b * 968 + srow];
  else if (srow < 974) p = p1[b * 6 + (srow - 968)];
  else                 p = p2[b * 50 + (srow - 974)];
  const float pf = (float)p;
  const float c0 = -0.07195578415606394f;

  const unsigned short* qrow = Qh + (((size_t)b * Hn + h) * Sn + srow) * DHn;
  bf16x8 qf[8];
#pragma unroll
  for (int dt = 0; dt < 8; ++dt)
    qf[dt] = *(const bf16x8*)(qrow + dt * 32 + lg * 8);
#pragma unroll
  for (int dt = 0; dt < 4; ++dt) {
#pragma unroll
    for (int j = 0; j < 8; ++j) {
      const int d = dt * 32 + lg * 8 + j;
      const float inv = __expf(c0 * (float)d);
      float cs, sn;
      sincosf(pf * inv, &sn, &cs);
      const float x1 = bf2f((unsigned short)qf[dt][j]);
      const float x2 = bf2f((unsigned short)qf[dt + 4][j]);
      qf[dt][j]     = (short)f2bf(x1 * cs - x2 * sn);
      qf[dt + 4][j] = (short)f2bf(x2 * cs + x1 * sn);
    }
  }

  f32x4 accO[16];
#pragma unroll
  for (int i = 0; i < 16; ++i) accO[i] = (f32x4){0.f, 0.f, 0.f, 0.f};
  float lsum[4] = {0.f, 0.f, 0.f, 0.f};

  const char* KgB = (const char*)(Kh + (size_t)b * Sn * DHn);
  const char* VgB = (const char*)(Vt + (size_t)b * DHn * Sn);
  const float* mbase = mask + (size_t)b * Sn * Sn + (size_t)(qr0 + lg * 4) * Sn;

  auto stage = [&](int kt, int nb) {
    const char* kg = KgB + (size_t)kt * 16384;
    const char* vg = VgB + (size_t)kt * 64;
#pragma unroll
    for (int j = 0; j < 2; ++j) {
      const int chunk = w * 2 + j;
      const int o = chunk * 1024 + l * 16;
      const int srcK = o ^ (((o >> 9) & 7) << 4);
      gload_lds16(kg + srcK, (char*)&KsB[nb][0] + chunk * 1024);
    }
#pragma unroll
    for (int j = 0; j < 2; ++j) {
      const int chunk = w * 2 + j;
      const int o = chunk * 1024 + l * 16;
      const int x = o ^ (((o >> 7) & 3) << 4);
      gload_lds16(vg + (size_t)(x >> 6) * 2048 + (x & 63),
                  (char*)&VsB[nb][0] + chunk * 1024);
    }
  };

  stage(0, 0);
  int cur = 0;
  for (int kt = 0; kt < 32; ++kt) {
    const int k0 = kt * 32;
    if (kt + 1 < 32) {
      stage(kt + 1, cur ^ 1);
      asm volatile("s_waitcnt vmcnt(4)" ::: "memory");
    } else {
      asm volatile("s_waitcnt vmcnt(0)" ::: "memory");
    }
    __builtin_amdgcn_s_barrier();
    __builtin_amdgcn_sched_barrier(0);

    const short* Ks = &KsB[cur][0];
    const short* Vs = &VsB[cur][0];

    float mv[8];
#pragma unroll
    for (int ct = 0; ct < 2; ++ct)
#pragma unroll
      for (int r = 0; r < 4; ++r)
        mv[ct * 4 + r] = mbase[(size_t)r * Sn + k0 + ct * 16 + lc];

    f32x4 sc[2];
    __builtin_amdgcn_s_setprio(1);
#pragma unroll
    for (int ct = 0; ct < 2; ++ct) {
      f32x4 acc = (f32x4){0.f, 0.f, 0.f, 0.f};
      const int row = ct * 16 + lc;
      const int sw = (row & 7) << 4;
#pragma unroll
      for (int dt = 0; dt < 8; ++dt) {
        const int byt = (row * 512 + dt * 64 + lg * 16) ^ sw;
        const bf16x8 kf = *(const bf16x8*)((const char*)Ks + byt);
        acc = __builtin_amdgcn_mfma_f32_16x16x32_bf16(qf[dt], kf, acc, 0, 0, 0);
      }
      sc[ct] = acc;
    }
    __builtin_amdgcn_s_setprio(0);

#pragma unroll
    for (int ct = 0; ct < 2; ++ct) {
#pragma unroll
      for (int r = 0; r < 4; ++r) {
        float x = sc[ct][r] * 1.25e-3f;
        x = fminf(fmaxf(x, -8.f), 8.f);
        const float e2 = __expf(2.f * x);
        const float capv = 50.f * (e2 - 1.f) / (e2 + 1.f);
        const float pv = __expf(capv + mv[ct * 4 + r] - 50.f);
        lsum[r] += pv;
        Pb[w][lg * 4 + r][ct * 16 + lc] = (short)f2bf(pv);
      }
    }
    const bf16x8 pfr = *(const bf16x8*)(&Pb[w][lc][lg * 8]);

    __builtin_amdgcn_s_setprio(1);
#pragma unroll
    for (int nt = 0; nt < 16; ++nt) {
      const int row = nt * 16 + lc;
      const int byt = (row * 64 + lg * 16) ^ (((row >> 1) & 3) << 4);
      const bf16x8 vf = *(const bf16x8*)((const char*)Vs + byt);
      accO[nt] = __builtin_amdgcn_mfma_f32_16x16x32_bf16(pfr, vf, accO[nt], 0, 0, 0);
    }
    __builtin_amdgcn_s_setprio(0);

    __builtin_amdgcn_s_barrier();
    cur ^= 1;
  }

#pragma unroll
  for (int mm = 1; mm < 16; mm <<= 1) {
#pragma unroll
    for (int r = 0; r < 4; ++r) lsum[r] += __shfl_xor(lsum[r], mm);
  }
  float rinv[4];
#pragma unroll
  for (int r = 0; r < 4; ++r) rinv[r] = 1.f / lsum[r];

  unsigned short* obase = O + ((size_t)b * Sn + qr0 + lg * 4) * HDn + h * DHn + lc;
#pragma unroll
  for (int nt = 0; nt < 16; ++nt)
#pragma unroll
    for (int r = 0; r < 4; ++r)
      obase[(size_t)r * HDn + nt * 16] = f2bf(accO[nt][r] * rinv[r]);
}

// ---------------------------------------------------------------------------
extern "C" void kernel_launch(void* const* d_in, const int* in_sizes, int n_in,
                              void* d_out, int out_size, void* d_ws, size_t ws_size,
                              hipStream_t stream) {
  (void)in_sizes; (void)n_in; (void)out_size; (void)ws_size;
  const float* hs0  = (const float*)d_in[0];
  const float* hs1  = (const float*)d_in[1];
  const float* hs2  = (const float*)d_in[2];
  const float* mask = (const float*)d_in[3];
  const int*   pos0 = (const int*)d_in[4];
  const int*   pos1 = (const int*)d_in[5];
  const int*   pos2 = (const int*)d_in[6];
  const float* wq[3] = {(const float*)d_in[7],  (const float*)d_in[11], (const float*)d_in[15]};
  const float* wk[3] = {(const float*)d_in[8],  (const float*)d_in[12], (const float*)d_in[16]};
  const float* wv[3] = {(const float*)d_in[9],  (const float*)d_in[13], (const float*)d_in[17]};
  const float* wo[3] = {(const float*)d_in[10], (const float*)d_in[14], (const float*)d_in[18]};
  float* out = (float*)d_out;

  // ws: Qh (33.5 MB; reused for woT after attn) | Kh | Vt | Ob (33.5 MB;
  //     first 21 MB hold qkvT until attn overwrites).
  // d_out doubles as scratch for hsT (33.3 MB) until gemm_wo writes it.
  unsigned short* Qh = (unsigned short*)d_ws;
  unsigned short* Kh = Qh + (size_t)Bn * Sn * HDn;
  unsigned short* Vt = Kh + (size_t)Bn * Sn * DHn;
  unsigned short* Ob = Vt + (size_t)Bn * Sn * DHn;
  unsigned short* qkvT = Ob;                     // dead until attn
  unsigned short* woT  = Qh;                     // dead after attn
  unsigned short* hsT  = (unsigned short*)out;   // dead once gemm_qkv done

  const int  Ls[3]   = {968, 6, 50};
  const int  offs[3] = {0, 968, 974};
  const int  Ks_[3]  = {2048, 1024, 1024};
  const int  mbN[3]  = {61, 1, 4};               // ceil(Bn*L/128)
  const float* hs[3] = {hs0, hs1, hs2};

  size_t qb[3]; qb[0] = 0;
  qb[1] = qb[0] + (size_t)20 * (Ks_[0] >> 6) * 8192;
  qb[2] = qb[1] + (size_t)20 * (Ks_[1] >> 6) * 8192;
  size_t ob[3]; ob[0] = 0;
  ob[1] = ob[0] + (size_t)16 * 32 * 8192;
  ob[2] = ob[1] + (size_t)8 * 32 * 8192;
  size_t hb[3]; hb[0] = 0;
  hb[1] = hb[0] + (size_t)mbN[0] * (Ks_[0] >> 6) * 8192;
  hb[2] = hb[1] + (size_t)mbN[1] * (Ks_[1] >> 6) * 8192;

  // --- convert QKV weights (into Ob region) and activations (into d_out) ---
  for (int g = 0; g < 3; ++g) {
    const int K = Ks_[g], kbN = K >> 6;
    hipLaunchKernelGGL(convW, dim3(16, kbN), dim3(256), 0, stream,
                       wq[g], qkvT + qb[g], K, HDn);
    hipLaunchKernelGGL(convW, dim3(2, kbN), dim3(256), 0, stream,
                       wk[g], qkvT + qb[g] + (size_t)16 * kbN * 8192, K, DHn);
    hipLaunchKernelGGL(convW, dim3(2, kbN), dim3(256), 0, stream,
                       wv[g], qkvT + qb[g] + (size_t)18 * kbN * 8192, K, DHn);
    hipLaunchKernelGGL(conv_hs, dim3(mbN[g], kbN), dim3(256), 0, stream,
                       hs[g], hsT + hb[g], K, Bn * Ls[g]);
  }

  // --- QKV projections (pure gload_lds both sides) ---
  for (int g = 0; g < 3; ++g) {
    const int L = Ls[g], K = Ks_[g], off = offs[g], M = Bn * L;
    hipLaunchKernelGGL(gemm_qkv, dim3(20, mbN[g]), dim3(256), 0, stream,
                       hsT + hb[g], qkvT + qb[g], Qh, Kh, Vt, L, K, off, M);
  }

  hipLaunchKernelGGL(rope_k, dim3(Bn * Sn), dim3(128), 0, stream, Kh, pos0, pos1, pos2);
  hipLaunchKernelGGL(attn_mfma, dim3(Sn / 128, Hn, Bn), dim3(512), 0, stream,
                     Qh, Kh, Vt, mask, pos0, pos1, pos2, Ob);

  // --- convert WO weights into woT (Qh region, dead after attn) ---
  for (int g = 0; g < 3; ++g) {
    const int N = (g == 0) ? 2048 : 1024;
    hipLaunchKernelGGL(convW, dim3(N / 128, 32), dim3(256), 0, stream,
                       wo[g], woT + ob[g], HDn, N);
  }

  // --- output projections (overwrite hsT scratch region of d_out) ---
  size_t ooff = 0;
  for (int g = 0; g < 3; ++g) {
    const int L = Ls[g], N = (g == 0) ? 2048 : 1024, off = offs[g], M = Bn * L;
    hipLaunchKernelGGL(gemm_wo, dim3(N / 128, (M + 127) / 128), dim3(256), 0, stream,
                       Ob, woT + ob[g], out + ooff, L, N, off, M);
    ooff += (size_t)M * N;
  }
}

// Round 9
// 561.032 us; speedup vs baseline: 24.9369x; 1.0688x over previous
//
#include <hip/hip_runtime.h>
#include <hip/hip_bf16.h>
#include <math.h>

namespace {
constexpr int Bn = 8, Sn = 1024, Hn = 8, DHn = 256, HDn = 2048;
}

using bf16x8 = __attribute__((ext_vector_type(8))) short;
using f32x4  = __attribute__((ext_vector_type(4))) float;

__device__ __forceinline__ float bf2f(unsigned short u) {
  unsigned int x = ((unsigned int)u) << 16;
  return __builtin_bit_cast(float, x);
}
__device__ __forceinline__ unsigned short f2bf(float f) {
  unsigned int x = __builtin_bit_cast(unsigned int, f);
  x += 0x7fff + ((x >> 16) & 1);   // RNE
  return (unsigned short)(x >> 16);
}
__device__ __forceinline__ bf16x8 pack8(const float4& u, const float4& v) {
  bf16x8 r;
  r[0] = (short)f2bf(u.x); r[1] = (short)f2bf(u.y); r[2] = (short)f2bf(u.z); r[3] = (short)f2bf(u.w);
  r[4] = (short)f2bf(v.x); r[5] = (short)f2bf(v.y); r[6] = (short)f2bf(v.z); r[7] = (short)f2bf(v.w);
  return r;
}
__device__ __forceinline__ void gload_lds16(const void* g, void* l) {
  __builtin_amdgcn_global_load_lds(
      (const __attribute__((address_space(1))) void*)g,
      (__attribute__((address_space(3))) void*)l, 16, 0, 0);
}

// ---------------------------------------------------------------------------
// Chunk layout (convW / conv_hs / GEMMs): 128 rows x 64 k bf16 = 16 KB.
// row r, granule g at byte r*128 + ((g^(r&7))*16). Identity gload_lds image.
// ---------------------------------------------------------------------------
__global__ __launch_bounds__(256) void convW(
    const float* __restrict__ W, unsigned short* __restrict__ T, int K, int N)
{
  __shared__ float S[64][132];
  const int nb = blockIdx.x, kb = blockIdx.y;
  const int t = threadIdx.x;
  const int kl = t >> 5, nq = (t & 31) * 4;
  for (int kk = kl; kk < 64; kk += 8) {
    const float4 v = *(const float4*)(W + (size_t)(kb * 64 + kk) * N + nb * 128 + nq);
    S[kk][nq] = v.x; S[kk][nq + 1] = v.y; S[kk][nq + 2] = v.z; S[kk][nq + 3] = v.w;
  }
  __syncthreads();
  unsigned short* chunk = T + ((size_t)nb * (K >> 6) + kb) * 8192;
#pragma unroll
  for (int j = 0; j < 4; ++j) {
    const int q = t * 4 + j;
    const int r = q >> 3, g = q & 7;
    bf16x8 o;
#pragma unroll
    for (int e = 0; e < 8; ++e) o[e] = (short)f2bf(S[g * 8 + e][r]);
    *(bf16x8*)(chunk + r * 64 + ((g ^ (r & 7)) * 8)) = o;
  }
}

__global__ __launch_bounds__(256) void conv_hs(
    const float* __restrict__ A, unsigned short* __restrict__ T, int K, int M_total)
{
  const int mb = blockIdx.x, kb = blockIdx.y;
  const int kbN = K >> 6;
  unsigned short* chunk = T + ((size_t)mb * kbN + kb) * 8192;
#pragma unroll
  for (int j = 0; j < 4; ++j) {
    const int q = j * 256 + threadIdx.x;
    const int r = q >> 3, g = q & 7;
    int m = mb * 128 + r;
    if (m >= M_total) m = mb * 128;
    const float* src = A + (size_t)m * K + kb * 64 + g * 8;
    const float4 u = *(const float4*)(src);
    const float4 v = *(const float4*)(src + 4);
    *(bf16x8*)(chunk + r * 64 + ((g ^ (r & 7)) * 8)) = pack8(u, v);
  }
}

// ---------------------------------------------------------------------------
// QKV GEMM: both operands pre-tiled chunks via identity gload_lds.
// ---------------------------------------------------------------------------
__global__ __launch_bounds__(256) void gemm_qkv(
    const unsigned short* __restrict__ AT, const unsigned short* __restrict__ WT,
    unsigned short* __restrict__ Qh, unsigned short* __restrict__ Kh,
    unsigned short* __restrict__ Vt,
    int L, int K, int c_off, int M_total)
{
  __shared__ __align__(16) short As[2][8192];
  __shared__ __align__(16) short Bs[2][8192];
  const int tid = threadIdx.x;
  const int w  = tid >> 6, l = tid & 63;
  const int wm = w >> 1,  wn = w & 1;
  const int lc = l & 15,  lg = l >> 4;
  const int bx  = blockIdx.x;
  const int bm0 = blockIdx.y * 128;
  const int kbN = K >> 6;

  int region, nbL, cb0;
  if (bx < 16)      { region = 0; nbL = bx;      cb0 = bx * 128; }
  else if (bx < 18) { region = 1; nbL = bx - 16; cb0 = (bx - 16) * 128; }
  else              { region = 2; nbL = bx - 18; cb0 = (bx - 18) * 128; }
  const unsigned short* WTr = WT +
      (region == 0 ? (size_t)0 : (region == 1 ? (size_t)16 * kbN * 8192
                                              : (size_t)18 * kbN * 8192));
  const unsigned short* bChunk0 = WTr + (size_t)nbL * kbN * 8192;
  const unsigned short* aChunk0 = AT + (size_t)blockIdx.y * kbN * 8192;

  f32x4 acc[4][4];
#pragma unroll
  for (int i = 0; i < 4; ++i)
#pragma unroll
    for (int j = 0; j < 4; ++j) acc[i][j] = (f32x4){0.f, 0.f, 0.f, 0.f};

  auto issueA = [&](int kb, int nb) {
    const char* src = (const char*)(aChunk0 + (size_t)kb * 8192);
    char* dst = (char*)&As[nb][0];
#pragma unroll
    for (int j = 0; j < 4; ++j)
      gload_lds16(src + tid * 16 + j * 4096, dst + tid * 16 + j * 4096);
  };
  auto issueB = [&](int kb, int nb) {
    const char* src = (const char*)(bChunk0 + (size_t)kb * 8192);
    char* dst = (char*)&Bs[nb][0];
#pragma unroll
    for (int j = 0; j < 4; ++j)
      gload_lds16(src + tid * 16 + j * 4096, dst + tid * 16 + j * 4096);
  };

  issueA(0, 0); issueB(0, 0);
  for (int kt = 0; kt < kbN; ++kt) {
    const int cur = kt & 1;
    __builtin_amdgcn_s_barrier();
    if (kt + 1 < kbN) {
      issueA(kt + 1, cur ^ 1); issueB(kt + 1, cur ^ 1);
      asm volatile("s_waitcnt vmcnt(8)" ::: "memory");
    } else {
      asm volatile("s_waitcnt vmcnt(0)" ::: "memory");
    }
    __builtin_amdgcn_s_barrier();
    __builtin_amdgcn_sched_barrier(0);
#pragma unroll
    for (int kk = 0; kk < 2; ++kk) {
      bf16x8 af[4], bfg[4];
#pragma unroll
      for (int mi = 0; mi < 4; ++mi) {
        const int row = wm * 64 + mi * 16 + lc;
        af[mi] = *(const bf16x8*)((const char*)&As[cur][0] + row * 128 +
                                  (((kk * 4 + lg) ^ (row & 7)) * 16));
      }
#pragma unroll
      for (int ni = 0; ni < 4; ++ni) {
        const int row = wn * 64 + ni * 16 + lc;
        bfg[ni] = *(const bf16x8*)((const char*)&Bs[cur][0] + row * 128 +
                                   (((kk * 4 + lg) ^ (row & 7)) * 16));
      }
#pragma unroll
      for (int mi = 0; mi < 4; ++mi)
#pragma unroll
        for (int ni = 0; ni < 4; ++ni)
          acc[mi][ni] = __builtin_amdgcn_mfma_f32_16x16x32_bf16(af[mi], bfg[ni], acc[mi][ni], 0, 0, 0);
    }
  }

#pragma unroll
  for (int mi = 0; mi < 4; ++mi) {
    const int gm = bm0 + wm * 64 + mi * 16 + lg * 4;
#pragma unroll
    for (int r = 0; r < 4; ++r) {
      const int m = gm + r;
      if (m < M_total) {
        const int cb = m / L, cs = m - cb * L;
#pragma unroll
        for (int ni = 0; ni < 4; ++ni) {
          const int colL = cb0 + wn * 64 + ni * 16 + lc;
          const unsigned short v = f2bf(acc[mi][ni][r]);
          if (region == 0) {
            const int hh = colL >> 8, dd = colL & 255;
            Qh[(((size_t)cb * Hn + hh) * Sn + c_off + cs) * DHn + dd] = v;
          } else if (region == 1) {
            Kh[((size_t)cb * Sn + c_off + cs) * DHn + colL] = v;
          } else {
            Vt[((size_t)cb * DHn + colL) * Sn + c_off + cs] = v;
          }
        }
      }
    }
  }
}

// ---------------------------------------------------------------------------
// Output-projection GEMM (unchanged).
// ---------------------------------------------------------------------------
__global__ __launch_bounds__(256) void gemm_wo(
    const unsigned short* __restrict__ A, const unsigned short* __restrict__ WT,
    float* __restrict__ C, int L, int N, int a_off, int M_total)
{
  __shared__ __align__(16) short As[2][8192];
  __shared__ __align__(16) short Bs[2][8192];
  const int tid = threadIdx.x;
  const int w  = tid >> 6, l = tid & 63;
  const int wm = w >> 1,  wn = w & 1;
  const int lc = l & 15,  lg = l >> 4;
  const int bn0 = blockIdx.x * 128;
  const int bm0 = blockIdx.y * 128;
  const int kbN = 32;

  const unsigned short* chunk0 = WT + (size_t)blockIdx.x * kbN * 8192;

  const char* aRow[4];
  const int gpos = tid & 7;
#pragma unroll
  for (int j = 0; j < 4; ++j) {
    const int ml = (tid >> 3) + j * 32;
    int m = bm0 + ml;
    if (m >= M_total) m = 0;
    const int cb = m / L, cs = m - cb * L;
    const int gc = gpos ^ (ml & 7);
    aRow[j] = (const char*)(A + (size_t)(cb * Sn + a_off + cs) * HDn) + gc * 16;
  }

  f32x4 acc[4][4];
#pragma unroll
  for (int i = 0; i < 4; ++i)
#pragma unroll
    for (int j = 0; j < 4; ++j) acc[i][j] = (f32x4){0.f, 0.f, 0.f, 0.f};

  auto issueA = [&](int kb, int nb) {
    char* dst = (char*)&As[nb][0];
#pragma unroll
    for (int j = 0; j < 4; ++j)
      gload_lds16(aRow[j] + (size_t)kb * 128, dst + tid * 16 + j * 4096);
  };
  auto issueB = [&](int kb, int nb) {
    const char* src = (const char*)(chunk0 + (size_t)kb * 8192);
    char* dst = (char*)&Bs[nb][0];
#pragma unroll
    for (int j = 0; j < 4; ++j)
      gload_lds16(src + tid * 16 + j * 4096, dst + tid * 16 + j * 4096);
  };

  issueA(0, 0); issueB(0, 0);
  for (int kt = 0; kt < kbN; ++kt) {
    const int cur = kt & 1;
    __builtin_amdgcn_s_barrier();
    if (kt + 1 < kbN) {
      issueA(kt + 1, cur ^ 1); issueB(kt + 1, cur ^ 1);
      asm volatile("s_waitcnt vmcnt(8)" ::: "memory");
    } else {
      asm volatile("s_waitcnt vmcnt(0)" ::: "memory");
    }
    __builtin_amdgcn_s_barrier();
    __builtin_amdgcn_sched_barrier(0);
#pragma unroll
    for (int kk = 0; kk < 2; ++kk) {
      bf16x8 af[4], bfg[4];
#pragma unroll
      for (int mi = 0; mi < 4; ++mi) {
        const int row = wm * 64 + mi * 16 + lc;
        af[mi] = *(const bf16x8*)((const char*)&As[cur][0] + row * 128 +
                                  (((kk * 4 + lg) ^ (row & 7)) * 16));
      }
#pragma unroll
      for (int ni = 0; ni < 4; ++ni) {
        const int row = wn * 64 + ni * 16 + lc;
        bfg[ni] = *(const bf16x8*)((const char*)&Bs[cur][0] + row * 128 +
                                   (((kk * 4 + lg) ^ (row & 7)) * 16));
      }
#pragma unroll
      for (int mi = 0; mi < 4; ++mi)
#pragma unroll
        for (int ni = 0; ni < 4; ++ni)
          acc[mi][ni] = __builtin_amdgcn_mfma_f32_16x16x32_bf16(af[mi], bfg[ni], acc[mi][ni], 0, 0, 0);
    }
  }

#pragma unroll
  for (int mi = 0; mi < 4; ++mi) {
    const int gm = bm0 + wm * 64 + mi * 16 + lg * 4;
#pragma unroll
    for (int r = 0; r < 4; ++r) {
      const int m = gm + r;
      if (m < M_total) {
        const int cb = m / L, cs = m - cb * L;
#pragma unroll
        for (int ni = 0; ni < 4; ++ni) {
          const int col = bn0 + wn * 64 + ni * 16 + lc;
          C[(size_t)(cb * L + cs) * N + col] = acc[mi][ni][r];
        }
      }
    }
  }
}

// ---------------------------------------------------------------------------
// RoPE in place on bf16 K [b][s][256].
// ---------------------------------------------------------------------------
__global__ __launch_bounds__(128) void rope_k(
    unsigned short* __restrict__ Kh,
    const int* __restrict__ p0, const int* __restrict__ p1, const int* __restrict__ p2)
{
  const int t = blockIdx.x, b = t >> 10, s = t & 1023;
  int p;
  if (s < 968)      p = p0[b * 968 + s];
  else if (s < 974) p = p1[b * 6 + (s - 968)];
  else              p = p2[b * 50 + (s - 974)];
  const float pf = (float)p;
  const float c0 = -0.07195578415606394f;
  const int d = threadIdx.x;
  const float inv = __expf(c0 * (float)d);
  float cs, sn;
  sincosf(pf * inv, &sn, &cs);
  unsigned short* base = Kh + ((size_t)b * Sn + s) * DHn;
  const float x1 = bf2f(base[d]), x2 = bf2f(base[d + 128]);
  base[d]       = f2bf(x1 * cs - x2 * sn);
  base[d + 128] = f2bf(x2 * cs + x1 * sn);
}

// ---------------------------------------------------------------------------
// MFMA flash attention v4 — head-major waves.
// Block = (b, 16 q-rows) x ALL 8 heads; wave w = head w.
// K/V/mask staged to LDS via global_load_lds, dbuf, counted vmcnt(5).
// Mask tile (16x32 fp32, head-independent) shared by all waves.
// Softmax: pv = exp2(mv*log2e - 144.2695*rcp(exp2(sc*C1)+1))  (clamp-free).
// ---------------------------------------------------------------------------
__global__ __launch_bounds__(512) void attn_mfma(
    const unsigned short* __restrict__ Qh, const unsigned short* __restrict__ Kh,
    const unsigned short* __restrict__ Vt, const float* __restrict__ mask,
    const int* __restrict__ p0, const int* __restrict__ p1, const int* __restrict__ p2,
    unsigned short* __restrict__ O)
{
  __shared__ __align__(16) short KsB[2][8192];   // 32 keys x 512B, K-swizzled
  __shared__ __align__(16) short VsB[2][8192];   // 256 d x 64B, V-swizzled
  __shared__ __align__(16) float Ms[2][512];     // 16 q-rows x 32 keys
  __shared__ __align__(16) short Pb[8][512];     // per-wave P bounce, swizzled
  const int tid = threadIdx.x;
  const int w  = tid >> 6;          // wave = head
  const int l  = tid & 63;
  const int lc = l & 15;
  const int lg = l >> 4;
  const int q0 = blockIdx.x * 16;
  const int b  = blockIdx.z;
  const int srow = q0 + lc;

  const char* KgB = (const char*)(Kh + (size_t)b * Sn * DHn);
  const char* VgB = (const char*)(Vt + (size_t)b * DHn * Sn);

  // stage tile kt into buffer nb: per wave 2 K + 2 V + 1 mask (lanes<16)
  auto stage = [&](int kt, int nb) {
    const char* kg = KgB + (size_t)kt * 16384;
    const char* vg = VgB + (size_t)kt * 64;
#pragma unroll
    for (int j = 0; j < 2; ++j) {
      const int chunk = w * 2 + j;
      const int o = chunk * 1024 + l * 16;
      const int srcK = o ^ (((o >> 9) & 7) << 4);
      gload_lds16(kg + srcK, (char*)&KsB[nb][0] + chunk * 1024);
    }
#pragma unroll
    for (int j = 0; j < 2; ++j) {
      const int chunk = w * 2 + j;
      const int o = chunk * 1024 + l * 16;
      const int x = o ^ (((o >> 7) & 3) << 4);
      gload_lds16(vg + (size_t)(x >> 6) * 2048 + (x & 63),
                  (char*)&VsB[nb][0] + chunk * 1024);
    }
    // mask: rows 2w..2w+1 of the 16x32 tile
    if (l < 16) {
      const float* mg = mask + ((size_t)b * Sn + q0 + 2 * w + (l >> 3)) * Sn
                             + kt * 32 + (l & 7) * 4;
      gload_lds16(mg, (char*)&Ms[nb][0] + w * 256);
    }
  };

  stage(0, 0);   // in flight during Q-load + RoPE

  // ---- Q load + fused RoPE (head = w) ----
  int p;
  if (srow < 968)      p = p0[b * 968 + srow];
  else if (srow < 974) p = p1[b * 6 + (srow - 968)];
  else                 p = p2[b * 50 + (srow - 974)];
  const float pf = (float)p;
  const float c0 = -0.07195578415606394f;

  const unsigned short* qrow = Qh + (((size_t)b * Hn + w) * Sn + srow) * DHn;
  bf16x8 qf[8];
#pragma unroll
  for (int dt = 0; dt < 8; ++dt)
    qf[dt] = *(const bf16x8*)(qrow + dt * 32 + lg * 8);
#pragma unroll
  for (int dt = 0; dt < 4; ++dt) {
#pragma unroll
    for (int j = 0; j < 8; ++j) {
      const int d = dt * 32 + lg * 8 + j;
      const float inv = __expf(c0 * (float)d);
      float cs, sn;
      sincosf(pf * inv, &sn, &cs);
      const float x1 = bf2f((unsigned short)qf[dt][j]);
      const float x2 = bf2f((unsigned short)qf[dt + 4][j]);
      qf[dt][j]     = (short)f2bf(x1 * cs - x2 * sn);
      qf[dt + 4][j] = (short)f2bf(x2 * cs + x1 * sn);
    }
  }

  f32x4 accO[16];
#pragma unroll
  for (int i = 0; i < 16; ++i) accO[i] = (f32x4){0.f, 0.f, 0.f, 0.f};
  float lsum[4] = {0.f, 0.f, 0.f, 0.f};

  const float C1 = 3.6067376022e-3f;     // 2*(1/800)*log2(e)
  const float RC = -144.26950408889634f; // -100*log2(e)
  const float L2E = 1.4426950408889634f;

  int cur = 0;
  for (int kt = 0; kt < 32; ++kt) {
    if (kt + 1 < 32) {
      stage(kt + 1, cur ^ 1);
      asm volatile("s_waitcnt vmcnt(5)" ::: "memory");   // tile kt complete
    } else {
      asm volatile("s_waitcnt vmcnt(0)" ::: "memory");
    }
    __builtin_amdgcn_s_barrier();
    __builtin_amdgcn_sched_barrier(0);

    const short* Ks = &KsB[cur][0];
    const short* Vs = &VsB[cur][0];
    const float* Mw = &Ms[cur][0];

    // QK^T from swizzled K LDS
    f32x4 sc[2];
    __builtin_amdgcn_s_setprio(1);
#pragma unroll
    for (int ct = 0; ct < 2; ++ct) {
      f32x4 acc = (f32x4){0.f, 0.f, 0.f, 0.f};
      const int row = ct * 16 + lc;
      const int sw = (row & 7) << 4;
#pragma unroll
      for (int dt = 0; dt < 8; ++dt) {
        const int byt = (row * 512 + dt * 64 + lg * 16) ^ sw;
        const bf16x8 kf = *(const bf16x8*)((const char*)Ks + byt);
        acc = __builtin_amdgcn_mfma_f32_16x16x32_bf16(qf[dt], kf, acc, 0, 0, 0);
      }
      sc[ct] = acc;
    }
    __builtin_amdgcn_s_setprio(0);

    // soft-cap + mask + exp -> P (bf16) to swizzled wave-private LDS
#pragma unroll
    for (int ct = 0; ct < 2; ++ct) {
#pragma unroll
      for (int r = 0; r < 4; ++r) {
        const int row_p = lg * 4 + r;
        const float mv = Mw[row_p * 32 + ct * 16 + lc];
        const float e2 = __builtin_amdgcn_exp2f(sc[ct][r] * C1);
        const float rr = __builtin_amdgcn_rcpf(e2 + 1.f);
        const float pv = __builtin_amdgcn_exp2f(fmaf(rr, RC, mv * L2E));
        lsum[r] += pv;
        const int col = ct * 16 + lc;
        const int gp = (col >> 3) ^ ((row_p >> 1) & 3);
        *((short*)((char*)&Pb[w][0] + row_p * 64 + gp * 16 + (col & 7) * 2)) =
            (short)f2bf(pv);
      }
    }
    const int gp2 = lg ^ ((lc >> 1) & 3);
    const bf16x8 pfr = *(const bf16x8*)((const char*)&Pb[w][0] + lc * 64 + gp2 * 16);

    // PV from swizzled V LDS
    __builtin_amdgcn_s_setprio(1);
#pragma unroll
    for (int nt = 0; nt < 16; ++nt) {
      const int row = nt * 16 + lc;
      const int byt = (row * 64 + lg * 16) ^ (((row >> 1) & 3) << 4);
      const bf16x8 vf = *(const bf16x8*)((const char*)Vs + byt);
      accO[nt] = __builtin_amdgcn_mfma_f32_16x16x32_bf16(pfr, vf, accO[nt], 0, 0, 0);
    }
    __builtin_amdgcn_s_setprio(0);

    __builtin_amdgcn_s_barrier();   // buf[cur] fully consumed before restage
    cur ^= 1;
  }

#pragma unroll
  for (int mm = 1; mm < 16; mm <<= 1) {
#pragma unroll
    for (int r = 0; r < 4; ++r) lsum[r] += __shfl_xor(lsum[r], mm);
  }
  float rinv[4];
#pragma unroll
  for (int r = 0; r < 4; ++r) rinv[r] = 1.f / lsum[r];

  unsigned short* obase = O + ((size_t)b * Sn + q0 + lg * 4) * HDn + w * DHn + lc;
#pragma unroll
  for (int nt = 0; nt < 16; ++nt)
#pragma unroll
    for (int r = 0; r < 4; ++r)
      obase[(size_t)r * HDn + nt * 16] = f2bf(accO[nt][r] * rinv[r]);
}

// ---------------------------------------------------------------------------
extern "C" void kernel_launch(void* const* d_in, const int* in_sizes, int n_in,
                              void* d_out, int out_size, void* d_ws, size_t ws_size,
                              hipStream_t stream) {
  (void)in_sizes; (void)n_in; (void)out_size; (void)ws_size;
  const float* hs0  = (const float*)d_in[0];
  const float* hs1  = (const float*)d_in[1];
  const float* hs2  = (const float*)d_in[2];
  const float* mask = (const float*)d_in[3];
  const int*   pos0 = (const int*)d_in[4];
  const int*   pos1 = (const int*)d_in[5];
  const int*   pos2 = (const int*)d_in[6];
  const float* wq[3] = {(const float*)d_in[7],  (const float*)d_in[11], (const float*)d_in[15]};
  const float* wk[3] = {(const float*)d_in[8],  (const float*)d_in[12], (const float*)d_in[16]};
  const float* wv[3] = {(const float*)d_in[9],  (const float*)d_in[13], (const float*)d_in[17]};
  const float* wo[3] = {(const float*)d_in[10], (const float*)d_in[14], (const float*)d_in[18]};
  float* out = (float*)d_out;

  unsigned short* Qh = (unsigned short*)d_ws;
  unsigned short* Kh = Qh + (size_t)Bn * Sn * HDn;
  unsigned short* Vt = Kh + (size_t)Bn * Sn * DHn;
  unsigned short* Ob = Vt + (size_t)Bn * Sn * DHn;
  unsigned short* qkvT = Ob;                     // dead until attn
  unsigned short* woT  = Qh;                     // dead after attn
  unsigned short* hsT  = (unsigned short*)out;   // dead once gemm_qkv done

  const int  Ls[3]   = {968, 6, 50};
  const int  offs[3] = {0, 968, 974};
  const int  Ks_[3]  = {2048, 1024, 1024};
  const int  mbN[3]  = {61, 1, 4};
  const float* hs[3] = {hs0, hs1, hs2};

  size_t qb[3]; qb[0] = 0;
  qb[1] = qb[0] + (size_t)20 * (Ks_[0] >> 6) * 8192;
  qb[2] = qb[1] + (size_t)20 * (Ks_[1] >> 6) * 8192;
  size_t ob[3]; ob[0] = 0;
  ob[1] = ob[0] + (size_t)16 * 32 * 8192;
  ob[2] = ob[1] + (size_t)8 * 32 * 8192;
  size_t hb[3]; hb[0] = 0;
  hb[1] = hb[0] + (size_t)mbN[0] * (Ks_[0] >> 6) * 8192;
  hb[2] = hb[1] + (size_t)mbN[1] * (Ks_[1] >> 6) * 8192;

  for (int g = 0; g < 3; ++g) {
    const int K = Ks_[g], kbN = K >> 6;
    hipLaunchKernelGGL(convW, dim3(16, kbN), dim3(256), 0, stream,
                       wq[g], qkvT + qb[g], K, HDn);
    hipLaunchKernelGGL(convW, dim3(2, kbN), dim3(256), 0, stream,
                       wk[g], qkvT + qb[g] + (size_t)16 * kbN * 8192, K, DHn);
    hipLaunchKernelGGL(convW, dim3(2, kbN), dim3(256), 0, stream,
                       wv[g], qkvT + qb[g] + (size_t)18 * kbN * 8192, K, DHn);
    hipLaunchKernelGGL(conv_hs, dim3(mbN[g], kbN), dim3(256), 0, stream,
                       hs[g], hsT + hb[g], K, Bn * Ls[g]);
  }

  for (int g = 0; g < 3; ++g) {
    const int L = Ls[g], K = Ks_[g], off = offs[g], M = Bn * L;
    hipLaunchKernelGGL(gemm_qkv, dim3(20, mbN[g]), dim3(256), 0, stream,
                       hsT + hb[g], qkvT + qb[g], Qh, Kh, Vt, L, K, off, M);
  }

  hipLaunchKernelGGL(rope_k, dim3(Bn * Sn), dim3(128), 0, stream, Kh, pos0, pos1, pos2);
  hipLaunchKernelGGL(attn_mfma, dim3(Sn / 16, 1, Bn), dim3(512), 0, stream,
                     Qh, Kh, Vt, mask, pos0, pos1, pos2, Ob);

  for (int g = 0; g < 3; ++g) {
    const int N = (g == 0) ? 2048 : 1024;
    hipLaunchKernelGGL(convW, dim3(N / 128, 32), dim3(256), 0, stream,
                       wo[g], woT + ob[g], HDn, N);
  }

  size_t ooff = 0;
  for (int g = 0; g < 3; ++g) {
    const int L = Ls[g], N = (g == 0) ? 2048 : 1024, off = offs[g], M = Bn * L;
    hipLaunchKernelGGL(gemm_wo, dim3(N / 128, (M + 127) / 128), dim3(256), 0, stream,
                       Ob, woT + ob[g], out + ooff, L, N, off, M);
    ooff += (size_t)M * N;
  }
}

// Round 10
// 424.745 us; speedup vs baseline: 32.9383x; 1.3209x over previous
//
#include <hip/hip_runtime.h>
#include <hip/hip_bf16.h>
#include <math.h>

namespace {
constexpr int Bn = 8, Sn = 1024, Hn = 8, DHn = 256, HDn = 2048;
// chunk = 128 rows x 32 k bf16 = 4096 shorts = 8 KB.
// row r, content granule g (k in [g*8,g*8+8), g<4) at shorts r*32 + (g^((r>>1)&3))*8.
// qkvT segment bases (shorts): 20 nb x (K/32) kchunks x 4096
constexpr size_t QB0 = 0;
constexpr size_t QB1 = (size_t)20 * 64 * 4096;            // 5242880
constexpr size_t QB2 = QB1 + (size_t)20 * 32 * 4096;      // 7864320
// hsT bases (shorts): mb x (K/32) x 4096
constexpr size_t HB0 = 0;
constexpr size_t HB1 = (size_t)61 * 64 * 4096;            // 15990784
constexpr size_t HB2 = HB1 + (size_t)1 * 32 * 4096;       // 16121856
// woT bases (shorts): nb x 64 x 4096
constexpr size_t OB0 = 0;
constexpr size_t OB1 = (size_t)16 * 64 * 4096;            // 4194304
constexpr size_t OB2 = OB1 + (size_t)8 * 64 * 4096;       // 6291456
}

using bf16x8 = __attribute__((ext_vector_type(8))) short;
using f32x4  = __attribute__((ext_vector_type(4))) float;

__device__ __forceinline__ float bf2f(unsigned short u) {
  unsigned int x = ((unsigned int)u) << 16;
  return __builtin_bit_cast(float, x);
}
__device__ __forceinline__ unsigned short f2bf(float f) {
  unsigned int x = __builtin_bit_cast(unsigned int, f);
  x += 0x7fff + ((x >> 16) & 1);   // RNE
  return (unsigned short)(x >> 16);
}
__device__ __forceinline__ bf16x8 pack8(const float4& u, const float4& v) {
  bf16x8 r;
  r[0] = (short)f2bf(u.x); r[1] = (short)f2bf(u.y); r[2] = (short)f2bf(u.z); r[3] = (short)f2bf(u.w);
  r[4] = (short)f2bf(v.x); r[5] = (short)f2bf(v.y); r[6] = (short)f2bf(v.z); r[7] = (short)f2bf(v.w);
  return r;
}
__device__ __forceinline__ void gload_lds16(const void* g, void* l) {
  __builtin_amdgcn_global_load_lds(
      (const __attribute__((address_space(1))) void*)g,
      (__attribute__((address_space(3))) void*)l, 16, 0, 0);
}

// weight converter body: W [K][N] fp32 -> W^T chunk pair for 64-k slab kb.
__device__ __forceinline__ void convW_body(
    const float* __restrict__ W, unsigned short* __restrict__ dstBase,
    int K, int N, int nb, int kb, float (*S)[132], int t)
{
  const int kl = t >> 5, nq = (t & 31) * 4;
  for (int kk = kl; kk < 64; kk += 8) {
    const float4 v = *(const float4*)(W + (size_t)(kb * 64 + kk) * N + nb * 128 + nq);
    S[kk][nq] = v.x; S[kk][nq + 1] = v.y; S[kk][nq + 2] = v.z; S[kk][nq + 3] = v.w;
  }
  __syncthreads();
  unsigned short* chunk = dstBase + ((size_t)nb * (K >> 5) + kb * 2) * 4096;
#pragma unroll
  for (int j = 0; j < 4; ++j) {
    const int q = t * 4 + j;          // granule id over 64-k slab (1024 total)
    const int r = q >> 3, g = q & 7;
    bf16x8 o;
#pragma unroll
    for (int e = 0; e < 8; ++e) o[e] = (short)f2bf(S[g * 8 + e][r]);
    *(bf16x8*)(chunk + (g >> 2) * 4096 + r * 32 + (((g & 3) ^ ((r >> 1) & 3)) * 8)) = o;
  }
}

// ---------------------------------------------------------------------------
// convAll: all QKV weight + activation conversions in ONE launch (3312 blocks).
// ---------------------------------------------------------------------------
__global__ __launch_bounds__(256) void convAll(
    const float* __restrict__ wq0, const float* __restrict__ wk0, const float* __restrict__ wv0,
    const float* __restrict__ wq1, const float* __restrict__ wk1, const float* __restrict__ wv1,
    const float* __restrict__ wq2, const float* __restrict__ wk2, const float* __restrict__ wv2,
    const float* __restrict__ hs0, const float* __restrict__ hs1, const float* __restrict__ hs2,
    unsigned short* __restrict__ qkvT, unsigned short* __restrict__ hsT)
{
  __shared__ float S[64][132];
  const int bid = blockIdx.x;
  const int t = threadIdx.x;

  if (bid < 1280) {   // ---- weights ----
    const float* W; unsigned short* dst; int K, N, nb, kb;
    if (bid < 512)       { W = wq0; dst = qkvT + QB0;                  K = 2048; N = 2048; nb = bid & 15; kb = bid >> 4; }
    else if (bid < 576)  { int r = bid - 512;  W = wk0; dst = qkvT + QB0 + (size_t)16 * 64 * 4096; K = 2048; N = 256; nb = r & 1; kb = r >> 1; }
    else if (bid < 640)  { int r = bid - 576;  W = wv0; dst = qkvT + QB0 + (size_t)18 * 64 * 4096; K = 2048; N = 256; nb = r & 1; kb = r >> 1; }
    else if (bid < 896)  { int r = bid - 640;  W = wq1; dst = qkvT + QB1;                  K = 1024; N = 2048; nb = r & 15; kb = r >> 4; }
    else if (bid < 928)  { int r = bid - 896;  W = wk1; dst = qkvT + QB1 + (size_t)16 * 32 * 4096; K = 1024; N = 256; nb = r & 1; kb = r >> 1; }
    else if (bid < 960)  { int r = bid - 928;  W = wv1; dst = qkvT + QB1 + (size_t)18 * 32 * 4096; K = 1024; N = 256; nb = r & 1; kb = r >> 1; }
    else if (bid < 1216) { int r = bid - 960;  W = wq2; dst = qkvT + QB2;                  K = 1024; N = 2048; nb = r & 15; kb = r >> 4; }
    else if (bid < 1248) { int r = bid - 1216; W = wk2; dst = qkvT + QB2 + (size_t)16 * 32 * 4096; K = 1024; N = 256; nb = r & 1; kb = r >> 1; }
    else                 { int r = bid - 1248; W = wv2; dst = qkvT + QB2 + (size_t)18 * 32 * 4096; K = 1024; N = 256; nb = r & 1; kb = r >> 1; }
    convW_body(W, dst, K, N, nb, kb, S, t);
  } else {            // ---- activations ----
    const float* A; unsigned short* dst; int K, M_total, mb, kb;
    if (bid < 3232)      { int it = bid - 1280; A = hs0; dst = hsT + HB0; K = 2048; M_total = 7744; mb = it >> 5; kb = it & 31; }
    else if (bid < 3248) { int it = bid - 3232; A = hs1; dst = hsT + HB1; K = 1024; M_total = 48;   mb = 0;       kb = it; }
    else                 { int it = bid - 3248; A = hs2; dst = hsT + HB2; K = 1024; M_total = 400;  mb = it >> 4; kb = it & 15; }
    unsigned short* chunk = dst + ((size_t)mb * (K >> 5) + kb * 2) * 4096;
#pragma unroll
    for (int j = 0; j < 4; ++j) {
      const int q = j * 256 + t;
      const int r = q >> 3, g = q & 7;
      int m = mb * 128 + r;
      if (m >= M_total) m = mb * 128;
      const float* src = A + (size_t)m * K + kb * 64 + g * 8;
      const float4 u = *(const float4*)(src);
      const float4 v = *(const float4*)(src + 4);
      *(bf16x8*)(chunk + (g >> 2) * 4096 + r * 32 + (((g & 3) ^ ((r >> 1) & 3)) * 8)) = pack8(u, v);
    }
  }
}

// convWo: WO weight conversions (1024 blocks), after attn frees Qh.
__global__ __launch_bounds__(256) void convWo(
    const float* __restrict__ wo0, const float* __restrict__ wo1, const float* __restrict__ wo2,
    unsigned short* __restrict__ woT)
{
  __shared__ float S[64][132];
  const int bid = blockIdx.x;
  const float* W; unsigned short* dst; int N, nb, kb;
  if (bid < 512)      { W = wo0; dst = woT + OB0; N = 2048; nb = bid & 15; kb = bid >> 4; }
  else if (bid < 768) { int r = bid - 512; W = wo1; dst = woT + OB1; N = 1024; nb = r & 7; kb = r >> 3; }
  else                { int r = bid - 768; W = wo2; dst = woT + OB2; N = 1024; nb = r & 7; kb = r >> 3; }
  convW_body(W, dst, HDn, N, nb, kb, S, threadIdx.x);
}

// ---------------------------------------------------------------------------
// Merged QKV GEMM: one launch, 1320 blocks. BK=32, 32KB LDS, vmcnt(4).
// ---------------------------------------------------------------------------
__global__ __launch_bounds__(256) void gemm_qkv(
    const unsigned short* __restrict__ hsT, const unsigned short* __restrict__ qkvT,
    unsigned short* __restrict__ Qh, unsigned short* __restrict__ Kh,
    unsigned short* __restrict__ Vt)
{
  __shared__ __align__(16) short As[2][4096];
  __shared__ __align__(16) short Bs[2][4096];
  const int tid = threadIdx.x;
  const int w  = tid >> 6, l = tid & 63;
  const int wm = w >> 1,  wn = w & 1;
  const int lc = l & 15,  lg = l >> 4;

  // segment demux
  const int bid = blockIdx.x;
  int bx, by, L, K, c_off, M_total;
  const unsigned short *aBase, *wBase;
  if (bid < 1220)      { bx = bid % 20; by = bid / 20; L = 968; K = 2048; c_off = 0;   M_total = 7744; aBase = hsT + HB0; wBase = qkvT + QB0; }
  else if (bid < 1240) { bx = bid - 1220; by = 0;      L = 6;   K = 1024; c_off = 968; M_total = 48;   aBase = hsT + HB1; wBase = qkvT + QB1; }
  else                 { int r = bid - 1240; bx = r % 20; by = r / 20; L = 50; K = 1024; c_off = 974; M_total = 400; aBase = hsT + HB2; wBase = qkvT + QB2; }
  const int kcN = K >> 5;
  const int bm0 = by * 128;

  int region, nbL, cb0;
  if (bx < 16)      { region = 0; nbL = bx;      cb0 = bx * 128; }
  else if (bx < 18) { region = 1; nbL = bx - 16; cb0 = (bx - 16) * 128; }
  else              { region = 2; nbL = bx - 18; cb0 = (bx - 18) * 128; }
  const unsigned short* WTr = wBase +
      (region == 0 ? (size_t)0 : (region == 1 ? (size_t)16 * kcN * 4096
                                              : (size_t)18 * kcN * 4096));
  const char* bChunk0 = (const char*)(WTr + (size_t)nbL * kcN * 4096);
  const char* aChunk0 = (const char*)(aBase + (size_t)by * kcN * 4096);

  f32x4 acc[4][4];
#pragma unroll
  for (int i = 0; i < 4; ++i)
#pragma unroll
    for (int j = 0; j < 4; ++j) acc[i][j] = (f32x4){0.f, 0.f, 0.f, 0.f};

  auto issue = [&](int kc, int nb) {
    const char* sa = aChunk0 + (size_t)kc * 8192;
    const char* sb = bChunk0 + (size_t)kc * 8192;
    char* da = (char*)&As[nb][0];
    char* db = (char*)&Bs[nb][0];
    gload_lds16(sa + tid * 16, da + tid * 16);
    gload_lds16(sa + tid * 16 + 4096, da + tid * 16 + 4096);
    gload_lds16(sb + tid * 16, db + tid * 16);
    gload_lds16(sb + tid * 16 + 4096, db + tid * 16 + 4096);
  };

  issue(0, 0);
  for (int kt = 0; kt < kcN; ++kt) {
    const int cur = kt & 1;
    __builtin_amdgcn_s_barrier();          // prev compute done (buf cur^1 free)
    if (kt + 1 < kcN) {
      issue(kt + 1, cur ^ 1);
      asm volatile("s_waitcnt vmcnt(4)" ::: "memory");   // tile kt arrived
    } else {
      asm volatile("s_waitcnt vmcnt(0)" ::: "memory");
    }
    __builtin_amdgcn_s_barrier();
    __builtin_amdgcn_sched_barrier(0);
    bf16x8 af[4], bfg[4];
#pragma unroll
    for (int mi = 0; mi < 4; ++mi) {
      const int row = wm * 64 + mi * 16 + lc;
      af[mi] = *(const bf16x8*)((const char*)&As[cur][0] + row * 64 +
                                ((lg ^ ((row >> 1) & 3)) * 16));
    }
#pragma unroll
    for (int ni = 0; ni < 4; ++ni) {
      const int row = wn * 64 + ni * 16 + lc;
      bfg[ni] = *(const bf16x8*)((const char*)&Bs[cur][0] + row * 64 +
                                 ((lg ^ ((row >> 1) & 3)) * 16));
    }
#pragma unroll
    for (int mi = 0; mi < 4; ++mi)
#pragma unroll
      for (int ni = 0; ni < 4; ++ni)
        acc[mi][ni] = __builtin_amdgcn_mfma_f32_16x16x32_bf16(af[mi], bfg[ni], acc[mi][ni], 0, 0, 0);
  }

#pragma unroll
  for (int mi = 0; mi < 4; ++mi) {
    const int gm = bm0 + wm * 64 + mi * 16 + lg * 4;
#pragma unroll
    for (int r = 0; r < 4; ++r) {
      const int m = gm + r;
      if (m < M_total) {
        const int cb = m / L, cs = m - cb * L;
#pragma unroll
        for (int ni = 0; ni < 4; ++ni) {
          const int colL = cb0 + wn * 64 + ni * 16 + lc;
          const unsigned short v = f2bf(acc[mi][ni][r]);
          if (region == 0) {
            const int hh = colL >> 8, dd = colL & 255;
            Qh[(((size_t)cb * Hn + hh) * Sn + c_off + cs) * DHn + dd] = v;
          } else if (region == 1) {
            Kh[((size_t)cb * Sn + c_off + cs) * DHn + colL] = v;
          } else {
            Vt[((size_t)cb * DHn + colL) * Sn + c_off + cs] = v;
          }
        }
      }
    }
  }
}

// ---------------------------------------------------------------------------
// Merged output-projection GEMM: one launch, 1016 blocks. BK=32, vmcnt(4).
// A (Ob bf16) via per-lane pre-swizzled gload_lds; B from woT chunks.
// ---------------------------------------------------------------------------
__global__ __launch_bounds__(256) void gemm_wo(
    const unsigned short* __restrict__ A, const unsigned short* __restrict__ woT,
    float* __restrict__ C)
{
  __shared__ __align__(16) short As[2][4096];
  __shared__ __align__(16) short Bs[2][4096];
  const int tid = threadIdx.x;
  const int w  = tid >> 6, l = tid & 63;
  const int wm = w >> 1,  wn = w & 1;
  const int lc = l & 15,  lg = l >> 4;

  const int bid = blockIdx.x;
  int bx, by, L, N, a_off, M_total;
  const unsigned short* wb;
  float* Cg;
  if (bid < 976)      { bx = bid & 15; by = bid >> 4; L = 968; N = 2048; a_off = 0;   M_total = 7744; wb = woT + OB0; Cg = C; }
  else if (bid < 984) { bx = bid - 976; by = 0;       L = 6;   N = 1024; a_off = 968; M_total = 48;   wb = woT + OB1; Cg = C + (size_t)7744 * 2048; }
  else                { int r = bid - 984; bx = r & 7; by = r >> 3; L = 50; N = 1024; a_off = 974; M_total = 400; wb = woT + OB2; Cg = C + (size_t)7744 * 2048 + (size_t)48 * 1024; }
  const int bm0 = by * 128;
  const char* chunk0 = (const char*)(wb + (size_t)bx * 64 * 4096);

  // A per-lane sources: dest slot (tid,j) -> row r = (tid>>2)+j*64, pos p = tid&3
  // content granule gcont = p ^ ((r>>1)&3) = (tid&3) ^ ((tid>>3)&3)  (j-indep)
  const int gcont = (tid & 3) ^ ((tid >> 3) & 3);
  const char* aRow[2];
#pragma unroll
  for (int j = 0; j < 2; ++j) {
    int m = bm0 + (tid >> 2) + j * 64;
    if (m >= M_total) m = 0;
    const int cb = m / L, cs = m - cb * L;
    aRow[j] = (const char*)(A + (size_t)(cb * Sn + a_off + cs) * HDn) + gcont * 16;
  }

  f32x4 acc[4][4];
#pragma unroll
  for (int i = 0; i < 4; ++i)
#pragma unroll
    for (int j = 0; j < 4; ++j) acc[i][j] = (f32x4){0.f, 0.f, 0.f, 0.f};

  auto issue = [&](int kc, int nb) {
    char* da = (char*)&As[nb][0];
    char* db = (char*)&Bs[nb][0];
    gload_lds16(aRow[0] + (size_t)kc * 64, da + tid * 16);
    gload_lds16(aRow[1] + (size_t)kc * 64, da + tid * 16 + 4096);
    const char* sb = chunk0 + (size_t)kc * 8192;
    gload_lds16(sb + tid * 16, db + tid * 16);
    gload_lds16(sb + tid * 16 + 4096, db + tid * 16 + 4096);
  };

  issue(0, 0);
  for (int kt = 0; kt < 64; ++kt) {
    const int cur = kt & 1;
    __builtin_amdgcn_s_barrier();
    if (kt + 1 < 64) {
      issue(kt + 1, cur ^ 1);
      asm volatile("s_waitcnt vmcnt(4)" ::: "memory");
    } else {
      asm volatile("s_waitcnt vmcnt(0)" ::: "memory");
    }
    __builtin_amdgcn_s_barrier();
    __builtin_amdgcn_sched_barrier(0);
    bf16x8 af[4], bfg[4];
#pragma unroll
    for (int mi = 0; mi < 4; ++mi) {
      const int row = wm * 64 + mi * 16 + lc;
      af[mi] = *(const bf16x8*)((const char*)&As[cur][0] + row * 64 +
                                ((lg ^ ((row >> 1) & 3)) * 16));
    }
#pragma unroll
    for (int ni = 0; ni < 4; ++ni) {
      const int row = wn * 64 + ni * 16 + lc;
      bfg[ni] = *(const bf16x8*)((const char*)&Bs[cur][0] + row * 64 +
                                 ((lg ^ ((row >> 1) & 3)) * 16));
    }
#pragma unroll
    for (int mi = 0; mi < 4; ++mi)
#pragma unroll
      for (int ni = 0; ni < 4; ++ni)
        acc[mi][ni] = __builtin_amdgcn_mfma_f32_16x16x32_bf16(af[mi], bfg[ni], acc[mi][ni], 0, 0, 0);
  }

#pragma unroll
  for (int mi = 0; mi < 4; ++mi) {
    const int gm = bm0 + wm * 64 + mi * 16 + lg * 4;
#pragma unroll
    for (int r = 0; r < 4; ++r) {
      const int m = gm + r;
      if (m < M_total) {
        const int cb = m / L, cs = m - cb * L;
#pragma unroll
        for (int ni = 0; ni < 4; ++ni) {
          const int col = bx * 128 + wn * 64 + ni * 16 + lc;
          Cg[(size_t)(cb * L + cs) * N + col] = acc[mi][ni][r];
        }
      }
    }
  }
}

// ---------------------------------------------------------------------------
// RoPE in place on bf16 K [b][s][256].
// ---------------------------------------------------------------------------
__global__ __launch_bounds__(128) void rope_k(
    unsigned short* __restrict__ Kh,
    const int* __restrict__ p0, const int* __restrict__ p1, const int* __restrict__ p2)
{
  const int t = blockIdx.x, b = t >> 10, s = t & 1023;
  int p;
  if (s < 968)      p = p0[b * 968 + s];
  else if (s < 974) p = p1[b * 6 + (s - 968)];
  else              p = p2[b * 50 + (s - 974)];
  const float pf = (float)p;
  const float c0 = -0.07195578415606394f;
  const int d = threadIdx.x;
  const float inv = __expf(c0 * (float)d);
  float cs, sn;
  sincosf(pf * inv, &sn, &cs);
  unsigned short* base = Kh + ((size_t)b * Sn + s) * DHn;
  const float x1 = bf2f(base[d]), x2 = bf2f(base[d + 128]);
  base[d]       = f2bf(x1 * cs - x2 * sn);
  base[d + 128] = f2bf(x2 * cs + x1 * sn);
}

// ---------------------------------------------------------------------------
// MFMA flash attention (round-9 structure, unchanged).
// ---------------------------------------------------------------------------
__global__ __launch_bounds__(512) void attn_mfma(
    const unsigned short* __restrict__ Qh, const unsigned short* __restrict__ Kh,
    const unsigned short* __restrict__ Vt, const float* __restrict__ mask,
    const int* __restrict__ p0, const int* __restrict__ p1, const int* __restrict__ p2,
    unsigned short* __restrict__ O)
{
  __shared__ __align__(16) short KsB[2][8192];
  __shared__ __align__(16) short VsB[2][8192];
  __shared__ __align__(16) float Ms[2][512];
  __shared__ __align__(16) short Pb[8][512];
  const int tid = threadIdx.x;
  const int w  = tid >> 6;
  const int l  = tid & 63;
  const int lc = l & 15;
  const int lg = l >> 4;
  const int q0 = blockIdx.x * 16;
  const int b  = blockIdx.z;
  const int srow = q0 + lc;

  const char* KgB = (const char*)(Kh + (size_t)b * Sn * DHn);
  const char* VgB = (const char*)(Vt + (size_t)b * DHn * Sn);

  auto stage = [&](int kt, int nb) {
    const char* kg = KgB + (size_t)kt * 16384;
    const char* vg = VgB + (size_t)kt * 64;
#pragma unroll
    for (int j = 0; j < 2; ++j) {
      const int chunk = w * 2 + j;
      const int o = chunk * 1024 + l * 16;
      const int srcK = o ^ (((o >> 9) & 7) << 4);
      gload_lds16(kg + srcK, (char*)&KsB[nb][0] + chunk * 1024);
    }
#pragma unroll
    for (int j = 0; j < 2; ++j) {
      const int chunk = w * 2 + j;
      const int o = chunk * 1024 + l * 16;
      const int x = o ^ (((o >> 7) & 3) << 4);
      gload_lds16(vg + (size_t)(x >> 6) * 2048 + (x & 63),
                  (char*)&VsB[nb][0] + chunk * 1024);
    }
    if (l < 16) {
      const float* mg = mask + ((size_t)b * Sn + q0 + 2 * w + (l >> 3)) * Sn
                             + kt * 32 + (l & 7) * 4;
      gload_lds16(mg, (char*)&Ms[nb][0] + w * 256);
    }
  };

  stage(0, 0);

  int p;
  if (srow < 968)      p = p0[b * 968 + srow];
  else if (srow < 974) p = p1[b * 6 + (srow - 968)];
  else                 p = p2[b * 50 + (srow - 974)];
  const float pf = (float)p;
  const float c0 = -0.07195578415606394f;

  const unsigned short* qrow = Qh + (((size_t)b * Hn + w) * Sn + srow) * DHn;
  bf16x8 qf[8];
#pragma unroll
  for (int dt = 0; dt < 8; ++dt)
    qf[dt] = *(const bf16x8*)(qrow + dt * 32 + lg * 8);
#pragma unroll
  for (int dt = 0; dt < 4; ++dt) {
#pragma unroll
    for (int j = 0; j < 8; ++j) {
      const int d = dt * 32 + lg * 8 + j;
      const float inv = __expf(c0 * (float)d);
      float cs, sn;
      sincosf(pf * inv, &sn, &cs);
      const float x1 = bf2f((unsigned short)qf[dt][j]);
      const float x2 = bf2f((unsigned short)qf[dt + 4][j]);
      qf[dt][j]     = (short)f2bf(x1 * cs - x2 * sn);
      qf[dt + 4][j] = (short)f2bf(x2 * cs + x1 * sn);
    }
  }

  f32x4 accO[16];
#pragma unroll
  for (int i = 0; i < 16; ++i) accO[i] = (f32x4){0.f, 0.f, 0.f, 0.f};
  float lsum[4] = {0.f, 0.f, 0.f, 0.f};

  const float C1 = 3.6067376022e-3f;
  const float RC = -144.26950408889634f;
  const float L2E = 1.4426950408889634f;

  int cur = 0;
  for (int kt = 0; kt < 32; ++kt) {
    if (kt + 1 < 32) {
      stage(kt + 1, cur ^ 1);
      asm volatile("s_waitcnt vmcnt(5)" ::: "memory");
    } else {
      asm volatile("s_waitcnt vmcnt(0)" ::: "memory");
    }
    __builtin_amdgcn_s_barrier();
    __builtin_amdgcn_sched_barrier(0);

    const short* Ks = &KsB[cur][0];
    const short* Vs = &VsB[cur][0];
    const float* Mw = &Ms[cur][0];

    f32x4 sc[2];
    __builtin_amdgcn_s_setprio(1);
#pragma unroll
    for (int ct = 0; ct < 2; ++ct) {
      f32x4 acc = (f32x4){0.f, 0.f, 0.f, 0.f};
      const int row = ct * 16 + lc;
      const int sw = (row & 7) << 4;
#pragma unroll
      for (int dt = 0; dt < 8; ++dt) {
        const int byt = (row * 512 + dt * 64 + lg * 16) ^ sw;
        const bf16x8 kf = *(const bf16x8*)((const char*)Ks + byt);
        acc = __builtin_amdgcn_mfma_f32_16x16x32_bf16(qf[dt], kf, acc, 0, 0, 0);
      }
      sc[ct] = acc;
    }
    __builtin_amdgcn_s_setprio(0);

#pragma unroll
    for (int ct = 0; ct < 2; ++ct) {
#pragma unroll
      for (int r = 0; r < 4; ++r) {
        const int row_p = lg * 4 + r;
        const float mv = Mw[row_p * 32 + ct * 16 + lc];
        const float e2 = __builtin_amdgcn_exp2f(sc[ct][r] * C1);
        const float rr = __builtin_amdgcn_rcpf(e2 + 1.f);
        const float pv = __builtin_amdgcn_exp2f(fmaf(rr, RC, mv * L2E));
        lsum[r] += pv;
        const int col = ct * 16 + lc;
        const int gp = (col >> 3) ^ ((row_p >> 1) & 3);
        *((short*)((char*)&Pb[w][0] + row_p * 64 + gp * 16 + (col & 7) * 2)) =
            (short)f2bf(pv);
      }
    }
    const int gp2 = lg ^ ((lc >> 1) & 3);
    const bf16x8 pfr = *(const bf16x8*)((const char*)&Pb[w][0] + lc * 64 + gp2 * 16);

    __builtin_amdgcn_s_setprio(1);
#pragma unroll
    for (int nt = 0; nt < 16; ++nt) {
      const int row = nt * 16 + lc;
      const int byt = (row * 64 + lg * 16) ^ (((row >> 1) & 3) << 4);
      const bf16x8 vf = *(const bf16x8*)((const char*)Vs + byt);
      accO[nt] = __builtin_amdgcn_mfma_f32_16x16x32_bf16(pfr, vf, accO[nt], 0, 0, 0);
    }
    __builtin_amdgcn_s_setprio(0);

    __builtin_amdgcn_s_barrier();
    cur ^= 1;
  }

#pragma unroll
  for (int mm = 1; mm < 16; mm <<= 1) {
#pragma unroll
    for (int r = 0; r < 4; ++r) lsum[r] += __shfl_xor(lsum[r], mm);
  }
  float rinv[4];
#pragma unroll
  for (int r = 0; r < 4; ++r) rinv[r] = 1.f / lsum[r];

  unsigned short* obase = O + ((size_t)b * Sn + q0 + lg * 4) * HDn + w * DHn + lc;
#pragma unroll
  for (int nt = 0; nt < 16; ++nt)
#pragma unroll
    for (int r = 0; r < 4; ++r)
      obase[(size_t)r * HDn + nt * 16] = f2bf(accO[nt][r] * rinv[r]);
}

// ---------------------------------------------------------------------------
extern "C" void kernel_launch(void* const* d_in, const int* in_sizes, int n_in,
                              void* d_out, int out_size, void* d_ws, size_t ws_size,
                              hipStream_t stream) {
  (void)in_sizes; (void)n_in; (void)out_size; (void)ws_size;
  const float* hs0  = (const float*)d_in[0];
  const float* hs1  = (const float*)d_in[1];
  const float* hs2  = (const float*)d_in[2];
  const float* mask = (const float*)d_in[3];
  const int*   pos0 = (const int*)d_in[4];
  const int*   pos1 = (const int*)d_in[5];
  const int*   pos2 = (const int*)d_in[6];
  float* out = (float*)d_out;

  unsigned short* Qh = (unsigned short*)d_ws;
  unsigned short* Kh = Qh + (size_t)Bn * Sn * HDn;
  unsigned short* Vt = Kh + (size_t)Bn * Sn * DHn;
  unsigned short* Ob = Vt + (size_t)Bn * Sn * DHn;
  unsigned short* qkvT = Ob;                     // dead until attn
  unsigned short* woT  = Qh;                     // dead after attn
  unsigned short* hsT  = (unsigned short*)out;   // dead once gemm_qkv done

  hipLaunchKernelGGL(convAll, dim3(3312), dim3(256), 0, stream,
                     (const float*)d_in[7],  (const float*)d_in[8],  (const float*)d_in[9],
                     (const float*)d_in[11], (const float*)d_in[12], (const float*)d_in[13],
                     (const float*)d_in[15], (const float*)d_in[16], (const float*)d_in[17],
                     hs0, hs1, hs2, qkvT, hsT);

  hipLaunchKernelGGL(gemm_qkv, dim3(1320), dim3(256), 0, stream,
                     hsT, qkvT, Qh, Kh, Vt);

  hipLaunchKernelGGL(rope_k, dim3(Bn * Sn), dim3(128), 0, stream, Kh, pos0, pos1, pos2);
  hipLaunchKernelGGL(attn_mfma, dim3(Sn / 16, 1, Bn), dim3(512), 0, stream,
                     Qh, Kh, Vt, mask, pos0, pos1, pos2, Ob);

  hipLaunchKernelGGL(convWo, dim3(1024), dim3(256), 0, stream,
                     (const float*)d_in[10], (const float*)d_in[14], (const float*)d_in[18], woT);

  hipLaunchKernelGGL(gemm_wo, dim3(1016), dim3(256), 0, stream, Ob, woT, out);
}